// Round 10
// baseline (1386.744 us; speedup 1.0000x reference)
//
#include <hip/hip_runtime.h>
#include <hip/hip_bf16.h>

#define NN 10000
#define NE 320000
#define HD 128
#define NL 6
#define EPSV 1e-5f

typedef _Float16 half8  __attribute__((ext_vector_type(8)));
typedef _Float16 half4v __attribute__((ext_vector_type(4)));
typedef float    f32x4  __attribute__((ext_vector_type(4)));

__device__ __forceinline__ float relu_(float x){ return fmaxf(x, 0.0f); }

// ---------------- degree / scan / place (CSR build) ----------------

__global__ void k_degree(const int* __restrict__ dst, int* __restrict__ counts){
  int e = blockIdx.x*256 + threadIdx.x;
  if (e < NE) atomicAdd(&counts[dst[e]], 1);
}

__global__ void k_scan(const int* __restrict__ counts, int* __restrict__ offs, float* __restrict__ invc){
  __shared__ int lds[1024];
  __shared__ int base_s;
  int tid = threadIdx.x;
  if (tid==0) base_s = 0;
  __syncthreads();
  for (int start=0; start<NN; start+=1024){
    int i = start+tid;
    int vv = (i<NN)? counts[i] : 0;
    lds[tid]=vv; __syncthreads();
    for (int off=1; off<1024; off<<=1){
      int t = (tid>=off)? lds[tid-off] : 0;
      __syncthreads();
      lds[tid] += t;
      __syncthreads();
    }
    int incl = lds[tid];
    if (i<NN){
      offs[i] = base_s + incl - vv;
      invc[i] = 1.0f / fmaxf((float)vv, 1.0f);
    }
    __syncthreads();
    if (tid==1023) base_s += lds[1023];
    __syncthreads();
  }
  if (tid==0) offs[NN] = base_s;
}

__global__ void k_place(const int* __restrict__ src, const int* __restrict__ dst,
                        const int* __restrict__ offs, int* __restrict__ cursor, int* __restrict__ csr){
  int e = blockIdx.x*256 + threadIdx.x;
  if (e < NE){
    int d = dst[e];
    int p = atomicAdd(&cursor[d], 1);
    csr[offs[d]+p] = src[e];
  }
}

// ---------------- fold gf into first-layer biases + init mu/rstd ----------------

__global__ void k_biasfold(const float* __restrict__ dom, const float* __restrict__ tt,
                           const float* __restrict__ xg, const float* __restrict__ domn,
                           const float* __restrict__ tn,
                           const float* __restrict__ embW1, const float* __restrict__ embB1,
                           const float* __restrict__ msgW1, const float* __restrict__ msgB1,
                           const float* __restrict__ updW1, const float* __restrict__ updB1,
                           float* __restrict__ b1eff, float* __restrict__ mu, float* __restrict__ rstd){
  float gf[12];
  gf[0]=dom[0]; gf[1]=dom[1]; gf[2]=dom[2]; gf[3]=tt[0];
  gf[4]=xg[0]; gf[5]=xg[1]; gf[6]=xg[2]; gf[7]=xg[3];
  gf[8]=domn[0]; gf[9]=domn[1]; gf[10]=domn[2]; gf[11]=tn[0];
  int b = blockIdx.x, t = threadIdx.x;
  if (b==0){
    float s = embB1[t];
    #pragma unroll
    for (int k=0;k<12;++k) s += gf[k]*embW1[(7+k)*HD + t];
    b1eff[t] = s;
  } else if (b<=6){
    int l=b-1;
    float s = msgB1[l*HD+t];
    #pragma unroll
    for (int k=0;k<12;++k) s += gf[k]*msgW1[((size_t)l*157 + 145+k)*HD + t];
    b1eff[(1+l)*HD + t] = s;
  } else if (b<=12){
    int l=b-7;
    float s = updB1[l*HD+t];
    #pragma unroll
    for (int k=0;k<12;++k) s += gf[k]*updW1[((size_t)l*268 + 256+k)*HD + t];
    b1eff[(7+l)*HD + t] = s;
  } else {
    mu[t] = 0.f;
    rstd[t] = 1.f;
  }
}

// ---------------- embedding: hb = mlp2_relu([r,v,gf]) ----------------

__global__ void k_embed(const float* __restrict__ r, const float* __restrict__ v,
                        const float* __restrict__ W1, const float* __restrict__ b1e,
                        const float* __restrict__ W2, const float* __restrict__ b2,
                        float* __restrict__ hb){
  __shared__ alignas(16) float a1s[4][HD];
  int tid=threadIdx.x, wid=tid>>6, lane=tid&63;
  int gw = blockIdx.x*4 + wid;
  int f0=lane, f1=lane+64;
  float* a1 = a1s[wid];
  float b1f0=b1e[f0], b1f1=b1e[f1], b2f0=b2[f0], b2f1=b2[f1];
  for (int n=gw*4; n<gw*4+4; ++n){
    float in7[7];
    in7[0]=r[n];
    #pragma unroll
    for (int k=0;k<6;++k) in7[1+k]=v[n*6+k];
    float z0=b1f0, z1=b1f1;
    #pragma unroll
    for (int k=0;k<7;++k){ z0 += in7[k]*W1[k*HD+f0]; z1 += in7[k]*W1[k*HD+f1]; }
    a1[f0]=relu_(z0); a1[f1]=relu_(z1);
    float h0=b2f0, h1=b2f1;
    {
      float w0a[8], w1a[8], w0n[8], w1n[8];
      #pragma unroll
      for (int u=0;u<8;++u){ w0a[u]=W2[u*HD+f0]; w1a[u]=W2[u*HD+f1]; }
      for (int kb=0; kb<HD; kb+=8){
        if (kb+8 < HD){
          #pragma unroll
          for (int u=0;u<8;++u){ w0n[u]=W2[(kb+8+u)*HD+f0]; w1n[u]=W2[(kb+8+u)*HD+f1]; }
        }
        #pragma unroll
        for (int u=0;u<8;++u){
          float a=a1[kb+u];
          h0+=a*w0a[u]; h1+=a*w1a[u];
        }
        #pragma unroll
        for (int u=0;u<8;++u){ w0a[u]=w0n[u]; w1a[u]=w1n[u]; }
      }
    }
    hb[n*HD+f0]=relu_(h0); hb[n*HD+f1]=relu_(h1);
  }
}

// ---------------- P/Q = +-(hnorm @ W1_h) + node-feature folds ----------------
// P[n] = hn@W1[0:128] + v[n]@W1[128:134] + r[n]*W1[140] + b1eff
// Q[n] = -hn@W1[0:128] + v[n]@W1[134:140] + r[n]*W1[141]

__global__ void k_hW(const float* __restrict__ hb, const float* __restrict__ mu, const float* __restrict__ rstd,
                     const float* __restrict__ v, const float* __restrict__ r,
                     const float* __restrict__ W, const float* __restrict__ b1e,
                     float* __restrict__ P, float* __restrict__ Q){
  __shared__ alignas(16) float hs[4][HD*4];
  int tid=threadIdx.x, wid=tid>>6, lane=tid&63;
  int gw=blockIdx.x*4+wid;
  int f0=lane, f1=lane+64;
  float* h4 = hs[wid];
  int n0 = gw*4;
  float mu0=mu[f0], mu1=mu[f1], rs0=rstd[f0], rs1=rstd[f1];
  float4 hv0, hv1;
  hv0.x=(hb[(n0+0)*HD+f0]-mu0)*rs0; hv0.y=(hb[(n0+1)*HD+f0]-mu0)*rs0;
  hv0.z=(hb[(n0+2)*HD+f0]-mu0)*rs0; hv0.w=(hb[(n0+3)*HD+f0]-mu0)*rs0;
  hv1.x=(hb[(n0+0)*HD+f1]-mu1)*rs1; hv1.y=(hb[(n0+1)*HD+f1]-mu1)*rs1;
  hv1.z=(hb[(n0+2)*HD+f1]-mu1)*rs1; hv1.w=(hb[(n0+3)*HD+f1]-mu1)*rs1;
  *(float4*)&h4[f0*4]=hv0; *(float4*)&h4[f1*4]=hv1;
  float m0[4]={0,0,0,0}, m1[4]={0,0,0,0};
  {
    float w0a[8], w1a[8], w0n[8], w1n[8];
    #pragma unroll
    for (int u=0;u<8;++u){ w0a[u]=W[u*HD+f0]; w1a[u]=W[u*HD+f1]; }
    for (int kb=0; kb<HD; kb+=8){
      if (kb+8 < HD){
        #pragma unroll
        for (int u=0;u<8;++u){ w0n[u]=W[(kb+8+u)*HD+f0]; w1n[u]=W[(kb+8+u)*HD+f1]; }
      }
      #pragma unroll
      for (int u=0;u<8;++u){
        float4 a = *(const float4*)&h4[(kb+u)*4];
        float w0=w0a[u], w1=w1a[u];
        m0[0]+=a.x*w0; m1[0]+=a.x*w1;
        m0[1]+=a.y*w0; m1[1]+=a.y*w1;
        m0[2]+=a.z*w0; m1[2]+=a.z*w1;
        m0[3]+=a.w*w0; m1[3]+=a.w*w1;
      }
      #pragma unroll
      for (int u=0;u<8;++u){ w0a[u]=w0n[u]; w1a[u]=w1n[u]; }
    }
  }
  float wvi0[6], wvi1[6], wvj0[6], wvj1[6];
  #pragma unroll
  for (int x=0;x<6;++x){
    wvi0[x]=W[(128+x)*HD+f0]; wvi1[x]=W[(128+x)*HD+f1];
    wvj0[x]=W[(134+x)*HD+f0]; wvj1[x]=W[(134+x)*HD+f1];
  }
  float wri0=W[140*HD+f0], wri1=W[140*HD+f1];
  float wrj0=W[141*HD+f0], wrj1=W[141*HD+f1];
  float b10=b1e[f0], b11=b1e[f1];
  #pragma unroll
  for (int e=0;e<4;++e){
    int n = n0+e;
    float p0 = m0[e] + b10, p1 = m1[e] + b11;
    float q0 = -m0[e],      q1 = -m1[e];
    #pragma unroll
    for (int x=0;x<6;++x){
      float vx = v[n*6+x];
      p0 += vx*wvi0[x]; p1 += vx*wvi1[x];
      q0 += vx*wvj0[x]; q1 += vx*wvj1[x];
    }
    float rn = r[n];
    p0 += rn*wri0; p1 += rn*wri1;
    q0 += rn*wrj0; q1 += rn*wrj1;
    P[n*HD+f0]=p0; P[n*HD+f1]=p1;
    Q[n*HD+f0]=q0; Q[n*HD+f1]=q1;
  }
}

// ---------------- edge MLP via fp16-split MFMA, wave-cooperative ----------------
// 2500 blocks x 4 dst nodes. Single a1 buffer, TWO barriers per tile (proven protocol).
//   wave w owns output cols [32w, 32w+32) (t in {2w, 2w+1}).

__global__ __launch_bounds__(256,2) void k_edge(
    const float* __restrict__ P, const float* __restrict__ Q,
    const float* __restrict__ pos, const float* __restrict__ dom,
    const int* __restrict__ offs, const int* __restrict__ csr,
    const float* __restrict__ Wpd, const float* __restrict__ W2, const float* __restrict__ b2,
    const float* __restrict__ invc, float* __restrict__ agg,
    float* __restrict__ zsum, float* __restrict__ zsumsq){
  __shared__ alignas(16) _Float16 w1pd[128*32];     // [f][k]: k0..2 Whi, k3..5 Whi, k6..8 Wlo, rest 0
  __shared__ alignas(16) _Float16 a1hi[16*136];     // block-shared [edge][f]
  __shared__ alignas(16) _Float16 a1lo[16*136];
  int tid = threadIdx.x;
  if (blockIdx.x==0 && tid<HD){ zsum[tid]=0.f; zsumsq[tid]=0.f; }
  if (tid < 128){
    int f = tid;
    #pragma unroll
    for (int k=0;k<32;++k) w1pd[f*32+k] = (_Float16)0.f;
    #pragma unroll
    for (int x=0;x<3;++x){
      float w = Wpd[x*HD + f];
      _Float16 h = (_Float16)w;
      w1pd[f*32 + x]     = h;
      w1pd[f*32 + 3 + x] = h;
      w1pd[f*32 + 6 + x] = (_Float16)(w - (float)h);
    }
  }
  int wid = tid>>6, lane = tid&63, g = lane>>4, c = lane&15;
  int t0 = 2*wid, t1 = 2*wid+1;
  // register-resident W2 fragments for this wave's two col-tiles
  half8 w2h[4][2], w2l[4][2];
  #pragma unroll
  for (int ks=0; ks<4; ++ks){
    #pragma unroll
    for (int tt=0; tt<2; ++tt){
      int col = 16*(2*wid+tt) + c;
      half8 fh, fl;
      #pragma unroll
      for (int j=0;j<8;++j){
        float w = W2[(ks*32 + g*8 + j)*HD + col];
        _Float16 h = (_Float16)w;
        fh[j] = h;
        fl[j] = (_Float16)(w - (float)h);
      }
      w2h[ks][tt] = fh;
      w2l[ks][tt] = fl;
    }
  }
  float b2v0 = b2[16*t0 + c], b2v1 = b2[16*t1 + c];
  float dm0=dom[0], dm1=dom[1], dm2=dom[2];
  f32x4 zero4 = {0.f,0.f,0.f,0.f};
  __syncthreads();
  int n0 = blockIdx.x*4;
  for (int n = n0; n < n0+4; ++n){
    f32x4 pv0 = *(const f32x4*)(P + (size_t)n*HD + 16*t0 + 4*g);
    f32x4 pv1 = *(const f32x4*)(P + (size_t)n*HD + 16*t1 + 4*g);
    float pn0=pos[n*3+0], pn1=pos[n*3+1], pn2=pos[n*3+2];
    float acc0=0.f, acc1=0.f;
    int ib=offs[n], ie=offs[n+1];
    for (int base=ib; base<ie; base+=16){
      int nb = ie - base; if (nb>16) nb = 16;
      int sA = csr[base + ((c<nb)? c : nb-1)];
      float q0=pos[sA*3+0], q1=pos[sA*3+1], q2=pos[sA*3+2];
      float pd0,pd1,pd2;
      { float diff,sh,ds;
        diff=pn0-q0; sh=(pn0<q0)?-dm0:dm0; ds=diff-sh; pd0=(fabsf(diff)<fabsf(ds))?diff:ds;
        diff=pn1-q1; sh=(pn1<q1)?-dm1:dm1; ds=diff-sh; pd1=(fabsf(diff)<fabsf(ds))?diff:ds;
        diff=pn2-q2; sh=(pn2<q2)?-dm2:dm2; ds=diff-sh; pd2=(fabsf(diff)<fabsf(ds))?diff:ds;
      }
      _Float16 p0h = (_Float16)pd0, p1h = (_Float16)pd1, p2h = (_Float16)pd2;
      _Float16 p0l = (_Float16)(pd0 - (float)p0h);
      _Float16 p1l = (_Float16)(pd1 - (float)p1h);
      _Float16 p2l = (_Float16)(pd2 - (float)p2h);
      half8 pdf;
      #pragma unroll
      for (int j=0;j<8;++j) pdf[j]=(_Float16)0.f;
      if (g==0){ pdf[0]=p0h; pdf[1]=p1h; pdf[2]=p2h; pdf[3]=p0l; pdf[4]=p1l; pdf[5]=p2l; pdf[6]=p0h; pdf[7]=p1h; }
      else if (g==1){ pdf[0]=p2h; }
      // GEMM1 (swapped): d[tt][j] = z_pd[f=16t+4g+j][edge c]
      half8 w1f0 = *(const half8*)&w1pd[(16*t0 + c)*32 + g*8];
      half8 w1f1 = *(const half8*)&w1pd[(16*t1 + c)*32 + g*8];
      f32x4 d0 = __builtin_amdgcn_mfma_f32_16x16x32_f16(w1f0, pdf, zero4, 0,0,0);
      f32x4 d1 = __builtin_amdgcn_mfma_f32_16x16x32_f16(w1f1, pdf, zero4, 0,0,0);
      // z = d + P + Q; relu; fp16 split; write to shared a1 tile
      const float* Qs = Q + (size_t)sA*HD;
      f32x4 qv0 = *(const f32x4*)(Qs + 16*t0 + 4*g);
      f32x4 qv1 = *(const f32x4*)(Qs + 16*t1 + 4*g);
      half4v h0, l0, h1, l1;
      #pragma unroll
      for (int j=0;j<4;++j){
        float a = fmaxf(d0[j] + pv0[j] + qv0[j], 0.f);
        _Float16 hh = (_Float16)a;
        h0[j] = hh; l0[j] = (_Float16)(a - (float)hh);
        float b = fmaxf(d1[j] + pv1[j] + qv1[j], 0.f);
        _Float16 hb2 = (_Float16)b;
        h1[j] = hb2; l1[j] = (_Float16)(b - (float)hb2);
      }
      *(half4v*)&a1hi[c*136 + 16*t0 + 4*g] = h0;
      *(half4v*)&a1lo[c*136 + 16*t0 + 4*g] = l0;
      *(half4v*)&a1hi[c*136 + 16*t1 + 4*g] = h1;
      *(half4v*)&a1lo[c*136 + 16*t1 + 4*g] = l1;
      __syncthreads();
      // GEMM2: m[edge 4g+j][col 16t+c], A from shared LDS, B from registers
      f32x4 m0 = zero4, m1 = zero4;
      #pragma unroll
      for (int ks=0; ks<4; ++ks){
        half8 ah = *(const half8*)&a1hi[c*136 + ks*32 + g*8];
        half8 al = *(const half8*)&a1lo[c*136 + ks*32 + g*8];
        m0 = __builtin_amdgcn_mfma_f32_16x16x32_f16(ah, w2h[ks][0], m0, 0,0,0);
        m0 = __builtin_amdgcn_mfma_f32_16x16x32_f16(al, w2h[ks][0], m0, 0,0,0);
        m0 = __builtin_amdgcn_mfma_f32_16x16x32_f16(ah, w2l[ks][0], m0, 0,0,0);
        m1 = __builtin_amdgcn_mfma_f32_16x16x32_f16(ah, w2h[ks][1], m1, 0,0,0);
        m1 = __builtin_amdgcn_mfma_f32_16x16x32_f16(al, w2h[ks][1], m1, 0,0,0);
        m1 = __builtin_amdgcn_mfma_f32_16x16x32_f16(ah, w2l[ks][1], m1, 0,0,0);
      }
      if (nb == 16){
        acc0 += fmaxf(m0[0]+b2v0,0.f)+fmaxf(m0[1]+b2v0,0.f)+fmaxf(m0[2]+b2v0,0.f)+fmaxf(m0[3]+b2v0,0.f);
        acc1 += fmaxf(m1[0]+b2v1,0.f)+fmaxf(m1[1]+b2v1,0.f)+fmaxf(m1[2]+b2v1,0.f)+fmaxf(m1[3]+b2v1,0.f);
      } else {
        #pragma unroll
        for (int j=0;j<4;++j){
          if (4*g+j < nb){
            acc0 += fmaxf(m0[j]+b2v0, 0.f);
            acc1 += fmaxf(m1[j]+b2v1, 0.f);
          }
        }
      }
      __syncthreads();
    }
    acc0 += __shfl_xor(acc0, 16); acc0 += __shfl_xor(acc0, 32);
    acc1 += __shfl_xor(acc1, 16); acc1 += __shfl_xor(acc1, 32);
    if (g==0){
      float ic = invc[n];
      agg[n*HD + 16*t0 + c] = acc0*ic;
      agg[n*HD + 16*t1 + c] = acc1*ic;
    }
  }
}

// ---------------- update MLP + residual (in place) + stats ----------------

__global__ void k_upd(float* __restrict__ hb, const float* __restrict__ mu, const float* __restrict__ rstd,
                      const float* __restrict__ agg,
                      const float* __restrict__ U1, const float* __restrict__ b1e,
                      const float* __restrict__ U2, const float* __restrict__ b2,
                      float* __restrict__ sum, float* __restrict__ sumsq){
  __shared__ alignas(16) float xs[4][2*HD*4];
  __shared__ alignas(16) float a1s[4][HD*4];
  int tid=threadIdx.x, wid=tid>>6, lane=tid&63;
  int gw=blockIdx.x*4+wid;
  int f0=lane, f1=lane+64;
  float* x4=xs[wid];
  float* a1p=a1s[wid];
  int n0=gw*4;
  float mu0=mu[f0], mu1=mu[f1], rs0=rstd[f0], rs1=rstd[f1];
  float4 hv0,hv1,av0,av1;
  hv0.x=(hb[(n0+0)*HD+f0]-mu0)*rs0; hv0.y=(hb[(n0+1)*HD+f0]-mu0)*rs0;
  hv0.z=(hb[(n0+2)*HD+f0]-mu0)*rs0; hv0.w=(hb[(n0+3)*HD+f0]-mu0)*rs0;
  hv1.x=(hb[(n0+0)*HD+f1]-mu1)*rs1; hv1.y=(hb[(n0+1)*HD+f1]-mu1)*rs1;
  hv1.z=(hb[(n0+2)*HD+f1]-mu1)*rs1; hv1.w=(hb[(n0+3)*HD+f1]-mu1)*rs1;
  av0.x=agg[(n0+0)*HD+f0]; av0.y=agg[(n0+1)*HD+f0]; av0.z=agg[(n0+2)*HD+f0]; av0.w=agg[(n0+3)*HD+f0];
  av1.x=agg[(n0+0)*HD+f1]; av1.y=agg[(n0+1)*HD+f1]; av1.z=agg[(n0+2)*HD+f1]; av1.w=agg[(n0+3)*HD+f1];
  *(float4*)&x4[f0*4]=hv0; *(float4*)&x4[f1*4]=hv1;
  *(float4*)&x4[(HD+f0)*4]=av0; *(float4*)&x4[(HD+f1)*4]=av1;
  float b1f0=b1e[f0], b1f1=b1e[f1];
  float zf0[4]={b1f0,b1f0,b1f0,b1f0}, zf1[4]={b1f1,b1f1,b1f1,b1f1};
  {
    float w0a[8], w1a[8], w0n[8], w1n[8];
    #pragma unroll
    for (int u=0;u<8;++u){ w0a[u]=U1[u*HD+f0]; w1a[u]=U1[u*HD+f1]; }
    for (int kb=0; kb<2*HD; kb+=8){
      if (kb+8 < 2*HD){
        #pragma unroll
        for (int u=0;u<8;++u){ w0n[u]=U1[(kb+8+u)*HD+f0]; w1n[u]=U1[(kb+8+u)*HD+f1]; }
      }
      #pragma unroll
      for (int u=0;u<8;++u){
        float4 a = *(const float4*)&x4[(kb+u)*4];
        float w0=w0a[u], w1=w1a[u];
        zf0[0]+=a.x*w0; zf1[0]+=a.x*w1;
        zf0[1]+=a.y*w0; zf1[1]+=a.y*w1;
        zf0[2]+=a.z*w0; zf1[2]+=a.z*w1;
        zf0[3]+=a.w*w0; zf1[3]+=a.w*w1;
      }
      #pragma unroll
      for (int u=0;u<8;++u){ w0a[u]=w0n[u]; w1a[u]=w1n[u]; }
    }
  }
  *(float4*)&a1p[f0*4] = make_float4(relu_(zf0[0]),relu_(zf0[1]),relu_(zf0[2]),relu_(zf0[3]));
  *(float4*)&a1p[f1*4] = make_float4(relu_(zf1[0]),relu_(zf1[1]),relu_(zf1[2]),relu_(zf1[3]));
  float b2f0=b2[f0], b2f1=b2[f1];
  float uf0[4]={b2f0,b2f0,b2f0,b2f0}, uf1[4]={b2f1,b2f1,b2f1,b2f1};
  {
    float w0a[8], w1a[8], w0n[8], w1n[8];
    #pragma unroll
    for (int u=0;u<8;++u){ w0a[u]=U2[u*HD+f0]; w1a[u]=U2[u*HD+f1]; }
    for (int kb=0; kb<HD; kb+=8){
      if (kb+8 < HD){
        #pragma unroll
        for (int u=0;u<8;++u){ w0n[u]=U2[(kb+8+u)*HD+f0]; w1n[u]=U2[(kb+8+u)*HD+f1]; }
      }
      #pragma unroll
      for (int u=0;u<8;++u){
        float4 a = *(const float4*)&a1p[(kb+u)*4];
        float w0=w0a[u], w1=w1a[u];
        uf0[0]+=a.x*w0; uf1[0]+=a.x*w1;
        uf0[1]+=a.y*w0; uf1[1]+=a.y*w1;
        uf0[2]+=a.z*w0; uf1[2]+=a.z*w1;
        uf0[3]+=a.w*w0; uf1[3]+=a.w*w1;
      }
      #pragma unroll
      for (int u=0;u<8;++u){ w0a[u]=w0n[u]; w1a[u]=w1n[u]; }
    }
  }
  float hvs0[4]={hv0.x,hv0.y,hv0.z,hv0.w};
  float hvs1[4]={hv1.x,hv1.y,hv1.z,hv1.w};
  float s0=0,q0=0,s1=0,q1=0;
  #pragma unroll
  for (int e=0;e<4;++e){
    float b0 = hvs0[e] + relu_(uf0[e]);
    float b1v = hvs1[e] + relu_(uf1[e]);
    hb[(n0+e)*HD+f0]=b0; hb[(n0+e)*HD+f1]=b1v;
    s0+=b0; q0+=b0*b0; s1+=b1v; q1+=b1v*b1v;
  }
  atomicAdd(&sum[f0], s0); atomicAdd(&sumsq[f0], q0);
  atomicAdd(&sum[f1], s1); atomicAdd(&sumsq[f1], q1);
}

__global__ void k_normfin(const float* __restrict__ sum, const float* __restrict__ sumsq,
                          float* __restrict__ mu, float* __restrict__ rstd){
  int t=threadIdx.x;
  float m = sum[t]*(1.0f/NN);
  float var = sumsq[t]*(1.0f/NN) - m*m;
  mu[t]=m;
  rstd[t]=rsqrtf(fmaxf(var,0.0f)+EPSV);
}

// ---------------- decoder + outputs ----------------

__global__ void k_out(const float* __restrict__ hb, const float* __restrict__ mu, const float* __restrict__ rstd,
                      const float* __restrict__ pos, const float* __restrict__ v,
                      const float* __restrict__ W1, const float* __restrict__ b1,
                      const float* __restrict__ W2, const float* __restrict__ b2,
                      const float* __restrict__ domn, float* __restrict__ out){
  __shared__ alignas(16) float hs[4][HD*4];
  __shared__ alignas(16) float a1s[4][HD*4];
  int tid=threadIdx.x, wid=tid>>6, lane=tid&63;
  int gw=blockIdx.x*4+wid;
  int f0=lane, f1=lane+64;
  float* h4=hs[wid];
  float* a1p=a1s[wid];
  int n0=gw*4;
  float mu0=mu[f0], mu1=mu[f1], rs0=rstd[f0], rs1=rstd[f1];
  float4 hv0,hv1;
  hv0.x=(hb[(n0+0)*HD+f0]-mu0)*rs0; hv0.y=(hb[(n0+1)*HD+f0]-mu0)*rs0;
  hv0.z=(hb[(n0+2)*HD+f0]-mu0)*rs0; hv0.w=(hb[(n0+3)*HD+f0]-mu0)*rs0;
  hv1.x=(hb[(n0+0)*HD+f1]-mu1)*rs1; hv1.y=(hb[(n0+1)*HD+f1]-mu1)*rs1;
  hv1.z=(hb[(n0+2)*HD+f1]-mu1)*rs1; hv1.w=(hb[(n0+3)*HD+f1]-mu1)*rs1;
  *(float4*)&h4[f0*4]=hv0; *(float4*)&h4[f1*4]=hv1;
  float b1f0=b1[f0], b1f1=b1[f1];
  float zf0[4]={b1f0,b1f0,b1f0,b1f0}, zf1[4]={b1f1,b1f1,b1f1,b1f1};
  {
    float w0a[8], w1a[8], w0n[8], w1n[8];
    #pragma unroll
    for (int u=0;u<8;++u){ w0a[u]=W1[u*HD+f0]; w1a[u]=W1[u*HD+f1]; }
    for (int kb=0; kb<HD; kb+=8){
      if (kb+8 < HD){
        #pragma unroll
        for (int u=0;u<8;++u){ w0n[u]=W1[(kb+8+u)*HD+f0]; w1n[u]=W1[(kb+8+u)*HD+f1]; }
      }
      #pragma unroll
      for (int u=0;u<8;++u){
        float4 a = *(const float4*)&h4[(kb+u)*4];
        float w0=w0a[u], w1=w1a[u];
        zf0[0]+=a.x*w0; zf1[0]+=a.x*w1;
        zf0[1]+=a.y*w0; zf1[1]+=a.y*w1;
        zf0[2]+=a.z*w0; zf1[2]+=a.z*w1;
        zf0[3]+=a.w*w0; zf1[3]+=a.w*w1;
      }
      #pragma unroll
      for (int u=0;u<8;++u){ w0a[u]=w0n[u]; w1a[u]=w1n[u]; }
    }
  }
  *(float4*)&a1p[f0*4] = make_float4(relu_(zf0[0]),relu_(zf0[1]),relu_(zf0[2]),relu_(zf0[3]));
  *(float4*)&a1p[f1*4] = make_float4(relu_(zf1[0]),relu_(zf1[1]),relu_(zf1[2]),relu_(zf1[3]));
  if (lane < 36){
    int e = lane/9, j = lane - e*9;
    int n = n0+e;
    float p = b2[j];
    float wp[8], wn[8];
    #pragma unroll
    for (int u=0;u<8;++u) wp[u]=W2[u*9+j];
    for (int kb=0; kb<HD; kb+=8){
      if (kb+8 < HD){
        #pragma unroll
        for (int u=0;u<8;++u) wn[u]=W2[(kb+8+u)*9+j];
      }
      #pragma unroll
      for (int u=0;u<8;++u) p += a1p[(kb+u)*4+e]*wp[u];
      #pragma unroll
      for (int u=0;u<8;++u) wp[u]=wn[u];
    }
    if (j<3){
      p += pos[n*3+j];
      float d = domn[j];
      p = p - floorf(p/d)*d;
      out[n*3+j] = p;
    } else {
      p += v[n*6 + (j-3)];
      out[3*NN + n*6 + (j-3)] = p;
    }
  }
}

__global__ void k_macro(const float* __restrict__ sum, const float* __restrict__ mu, const float* __restrict__ rstd,
                        const float* __restrict__ W1, const float* __restrict__ b1,
                        const float* __restrict__ W2, const float* __restrict__ b2,
                        float* __restrict__ out){
  __shared__ float hm[HD];
  __shared__ float as[HD];
  int t=threadIdx.x;
  hm[t] = (sum[t]*(1.0f/NN) - mu[t])*rstd[t];
  __syncthreads();
  float z=b1[t];
  for (int k=0;k<HD;++k) z += hm[k]*W1[k*HD+t];
  as[t]=relu_(z);
  __syncthreads();
  if (t<3){
    float p=b2[t];
    for (int k=0;k<HD;++k) p += as[k]*W2[k*3+t];
    out[9*NN+t]=p;
  }
}

// ---------------- host launch ----------------

extern "C" void kernel_launch(void* const* d_in, const int* in_sizes, int n_in,
                              void* d_out, int out_size, void* d_ws, size_t ws_size,
                              hipStream_t stream) {
  const float* v    = (const float*)d_in[0];
  const float* pos  = (const float*)d_in[1];
  const float* r    = (const float*)d_in[2];
  const float* dom  = (const float*)d_in[3];
  const float* tt   = (const float*)d_in[4];
  const float* xg   = (const float*)d_in[5];
  const float* domn = (const float*)d_in[6];
  const float* tn   = (const float*)d_in[7];
  const int*   eidx = (const int*)d_in[8];
  const float* embW1 = (const float*)d_in[10];
  const float* embB1 = (const float*)d_in[11];
  const float* embW2 = (const float*)d_in[12];
  const float* embB2 = (const float*)d_in[13];
  const float* msgW1 = (const float*)d_in[14];
  const float* msgB1 = (const float*)d_in[15];
  const float* msgW2 = (const float*)d_in[16];
  const float* msgB2 = (const float*)d_in[17];
  const float* updW1 = (const float*)d_in[18];
  const float* updB1 = (const float*)d_in[19];
  const float* updW2 = (const float*)d_in[20];
  const float* updB2 = (const float*)d_in[21];
  const float* outW1 = (const float*)d_in[22];
  const float* outB1 = (const float*)d_in[23];
  const float* outW2 = (const float*)d_in[24];
  const float* outB2 = (const float*)d_in[25];
  const float* macW1 = (const float*)d_in[26];
  const float* macB1 = (const float*)d_in[27];
  const float* macW2 = (const float*)d_in[28];
  const float* macB2 = (const float*)d_in[29];
  float* out = (float*)d_out;
  float* ws  = (float*)d_ws;

  float* hb    = ws;
  float* P     = ws + 1280000;
  float* Q     = ws + 2560000;
  float* agg   = ws + 3840000;
  float* invc  = ws + 5120000;
  float* b1eff = ws + 5130000;   // 13*128
  float* sum   = ws + 5131664;
  float* sumsq = ws + 5131792;
  float* mu    = ws + 5131920;
  float* rstd  = ws + 5132048;
  int* counts  = (int*)(ws + 5132304);
  int* offs    = counts + NN;       // NN+1
  int* cursor  = offs + NN + 1;
  int* csr     = cursor + NN;       // NE

  const int* srcA = eidx;
  const int* dstA = eidx + NE;

  hipMemsetAsync(counts, 0, NN*sizeof(int), stream);
  hipMemsetAsync(cursor, 0, NN*sizeof(int), stream);

  k_degree<<<(NE+255)/256, 256, 0, stream>>>(dstA, counts);
  k_scan<<<1, 1024, 0, stream>>>(counts, offs, invc);
  k_place<<<(NE+255)/256, 256, 0, stream>>>(srcA, dstA, offs, cursor, csr);
  k_biasfold<<<14, 128, 0, stream>>>(dom, tt, xg, domn, tn, embW1, embB1, msgW1, msgB1, updW1, updB1,
                                     b1eff, mu, rstd);
  k_embed<<<625, 256, 0, stream>>>(r, v, embW1, b1eff, embW2, embB2, hb);

  for (int l=0; l<NL; ++l){
    k_hW<<<625,256,0,stream>>>(hb, mu, rstd, v, r, msgW1 + (size_t)l*157*HD, b1eff + (1+l)*HD, P, Q);
    k_edge<<<2500,256,0,stream>>>(P, Q, pos, dom, offs, csr,
        msgW1 + ((size_t)l*157+142)*HD,
        msgW2 + (size_t)l*HD*HD, msgB2 + l*HD, invc, agg, sum, sumsq);
    k_upd<<<625,256,0,stream>>>(hb, mu, rstd, agg,
        updW1 + (size_t)l*268*HD, b1eff + (7+l)*HD,
        updW2 + (size_t)l*HD*HD, updB2 + l*HD, sum, sumsq);
    k_normfin<<<1,128,0,stream>>>(sum, sumsq, mu, rstd);
  }

  k_out<<<625,256,0,stream>>>(hb, mu, rstd, pos, v, outW1, outB1, outW2, outB2, domn, out);
  k_macro<<<1,128,0,stream>>>(sum, mu, rstd, macW1, macB1, macW2, macB2, out);
}

// Round 12
// 876.311 us; speedup vs baseline: 1.5825x; 1.5825x over previous
//
#include <hip/hip_runtime.h>
#include <hip/hip_bf16.h>

#define NN 10000
#define NE 320000
#define HD 128
#define NL 6
#define EPSV 1e-5f

typedef _Float16 half8  __attribute__((ext_vector_type(8)));
typedef _Float16 half4v __attribute__((ext_vector_type(4)));
typedef float    f32x4  __attribute__((ext_vector_type(4)));

__device__ __forceinline__ float relu_(float x){ return fmaxf(x, 0.0f); }

// ---------------- degree / scan / place (CSR build) ----------------

__global__ void k_degree(const int* __restrict__ dst, int* __restrict__ counts){
  int e = blockIdx.x*256 + threadIdx.x;
  if (e < NE) atomicAdd(&counts[dst[e]], 1);
}

__global__ void k_scan(const int* __restrict__ counts, int* __restrict__ offs, float* __restrict__ invc){
  __shared__ int lds[1024];
  __shared__ int base_s;
  int tid = threadIdx.x;
  if (tid==0) base_s = 0;
  __syncthreads();
  for (int start=0; start<NN; start+=1024){
    int i = start+tid;
    int vv = (i<NN)? counts[i] : 0;
    lds[tid]=vv; __syncthreads();
    for (int off=1; off<1024; off<<=1){
      int t = (tid>=off)? lds[tid-off] : 0;
      __syncthreads();
      lds[tid] += t;
      __syncthreads();
    }
    int incl = lds[tid];
    if (i<NN){
      offs[i] = base_s + incl - vv;
      invc[i] = 1.0f / fmaxf((float)vv, 1.0f);
    }
    __syncthreads();
    if (tid==1023) base_s += lds[1023];
    __syncthreads();
  }
  if (tid==0) offs[NN] = base_s;
}

__global__ void k_place(const int* __restrict__ src, const int* __restrict__ dst,
                        const int* __restrict__ offs, int* __restrict__ cursor, int* __restrict__ csr){
  int e = blockIdx.x*256 + threadIdx.x;
  if (e < NE){
    int d = dst[e];
    int p = atomicAdd(&cursor[d], 1);
    csr[offs[d]+p] = src[e];
  }
}

// ---------------- fold gf into first-layer biases + init mu/rstd ----------------

__global__ void k_biasfold(const float* __restrict__ dom, const float* __restrict__ tt,
                           const float* __restrict__ xg, const float* __restrict__ domn,
                           const float* __restrict__ tn,
                           const float* __restrict__ embW1, const float* __restrict__ embB1,
                           const float* __restrict__ msgW1, const float* __restrict__ msgB1,
                           const float* __restrict__ updW1, const float* __restrict__ updB1,
                           float* __restrict__ b1eff, float* __restrict__ mu, float* __restrict__ rstd){
  float gf[12];
  gf[0]=dom[0]; gf[1]=dom[1]; gf[2]=dom[2]; gf[3]=tt[0];
  gf[4]=xg[0]; gf[5]=xg[1]; gf[6]=xg[2]; gf[7]=xg[3];
  gf[8]=domn[0]; gf[9]=domn[1]; gf[10]=domn[2]; gf[11]=tn[0];
  int b = blockIdx.x, t = threadIdx.x;
  if (b==0){
    float s = embB1[t];
    #pragma unroll
    for (int k=0;k<12;++k) s += gf[k]*embW1[(7+k)*HD + t];
    b1eff[t] = s;
  } else if (b<=6){
    int l=b-1;
    float s = msgB1[l*HD+t];
    #pragma unroll
    for (int k=0;k<12;++k) s += gf[k]*msgW1[((size_t)l*157 + 145+k)*HD + t];
    b1eff[(1+l)*HD + t] = s;
  } else if (b<=12){
    int l=b-7;
    float s = updB1[l*HD+t];
    #pragma unroll
    for (int k=0;k<12;++k) s += gf[k]*updW1[((size_t)l*268 + 256+k)*HD + t];
    b1eff[(7+l)*HD + t] = s;
  } else {
    mu[t] = 0.f;
    rstd[t] = 1.f;
  }
}

// ---------------- embedding: hb = mlp2_relu([r,v,gf]) ----------------

__global__ void k_embed(const float* __restrict__ r, const float* __restrict__ v,
                        const float* __restrict__ W1, const float* __restrict__ b1e,
                        const float* __restrict__ W2, const float* __restrict__ b2,
                        float* __restrict__ hb){
  __shared__ alignas(16) float a1s[4][HD];
  int tid=threadIdx.x, wid=tid>>6, lane=tid&63;
  int gw = blockIdx.x*4 + wid;
  int f0=lane, f1=lane+64;
  float* a1 = a1s[wid];
  float b1f0=b1e[f0], b1f1=b1e[f1], b2f0=b2[f0], b2f1=b2[f1];
  for (int n=gw*4; n<gw*4+4; ++n){
    float in7[7];
    in7[0]=r[n];
    #pragma unroll
    for (int k=0;k<6;++k) in7[1+k]=v[n*6+k];
    float z0=b1f0, z1=b1f1;
    #pragma unroll
    for (int k=0;k<7;++k){ z0 += in7[k]*W1[k*HD+f0]; z1 += in7[k]*W1[k*HD+f1]; }
    a1[f0]=relu_(z0); a1[f1]=relu_(z1);
    float h0=b2f0, h1=b2f1;
    for (int k=0;k<HD;++k){ float a=a1[k]; h0+=a*W2[k*HD+f0]; h1+=a*W2[k*HD+f1]; }
    hb[n*HD+f0]=relu_(h0); hb[n*HD+f1]=relu_(h1);
  }
}

// ---------------- P/Q = +-(hnorm @ W1_h) + node-feature folds ----------------
// P[n] = hn@W1[0:128] + v[n]@W1[128:134] + r[n]*W1[140] + b1eff
// Q[n] = -hn@W1[0:128] + v[n]@W1[134:140] + r[n]*W1[141]

__global__ void k_hW(const float* __restrict__ hb, const float* __restrict__ mu, const float* __restrict__ rstd,
                     const float* __restrict__ v, const float* __restrict__ r,
                     const float* __restrict__ W, const float* __restrict__ b1e,
                     float* __restrict__ P, float* __restrict__ Q){
  __shared__ alignas(16) float hs[4][HD*4];
  int tid=threadIdx.x, wid=tid>>6, lane=tid&63;
  int gw=blockIdx.x*4+wid;
  int f0=lane, f1=lane+64;
  float* h4 = hs[wid];
  int n0 = gw*4;
  float mu0=mu[f0], mu1=mu[f1], rs0=rstd[f0], rs1=rstd[f1];
  float4 hv0, hv1;
  hv0.x=(hb[(n0+0)*HD+f0]-mu0)*rs0; hv0.y=(hb[(n0+1)*HD+f0]-mu0)*rs0;
  hv0.z=(hb[(n0+2)*HD+f0]-mu0)*rs0; hv0.w=(hb[(n0+3)*HD+f0]-mu0)*rs0;
  hv1.x=(hb[(n0+0)*HD+f1]-mu1)*rs1; hv1.y=(hb[(n0+1)*HD+f1]-mu1)*rs1;
  hv1.z=(hb[(n0+2)*HD+f1]-mu1)*rs1; hv1.w=(hb[(n0+3)*HD+f1]-mu1)*rs1;
  *(float4*)&h4[f0*4]=hv0; *(float4*)&h4[f1*4]=hv1;
  float m0[4]={0,0,0,0}, m1[4]={0,0,0,0};
  for (int k=0;k<HD;++k){
    float4 a = *(const float4*)&h4[k*4];
    float w0=W[k*HD+f0], w1=W[k*HD+f1];
    m0[0]+=a.x*w0; m1[0]+=a.x*w1;
    m0[1]+=a.y*w0; m1[1]+=a.y*w1;
    m0[2]+=a.z*w0; m1[2]+=a.z*w1;
    m0[3]+=a.w*w0; m1[3]+=a.w*w1;
  }
  float wvi0[6], wvi1[6], wvj0[6], wvj1[6];
  #pragma unroll
  for (int x=0;x<6;++x){
    wvi0[x]=W[(128+x)*HD+f0]; wvi1[x]=W[(128+x)*HD+f1];
    wvj0[x]=W[(134+x)*HD+f0]; wvj1[x]=W[(134+x)*HD+f1];
  }
  float wri0=W[140*HD+f0], wri1=W[140*HD+f1];
  float wrj0=W[141*HD+f0], wrj1=W[141*HD+f1];
  float b10=b1e[f0], b11=b1e[f1];
  #pragma unroll
  for (int e=0;e<4;++e){
    int n = n0+e;
    float p0 = m0[e] + b10, p1 = m1[e] + b11;
    float q0 = -m0[e],      q1 = -m1[e];
    #pragma unroll
    for (int x=0;x<6;++x){
      float vx = v[n*6+x];
      p0 += vx*wvi0[x]; p1 += vx*wvi1[x];
      q0 += vx*wvj0[x]; q1 += vx*wvj1[x];
    }
    float rn = r[n];
    p0 += rn*wri0; p1 += rn*wri1;
    q0 += rn*wrj0; q1 += rn*wrj1;
    P[n*HD+f0]=p0; P[n*HD+f1]=p1;
    Q[n*HD+f0]=q0; Q[n*HD+f1]=q1;
  }
}

// ---------------- edge MLP via fp16-split MFMA, wave-cooperative ----------------
// 2500 blocks x 4 dst nodes. Single a1 buffer, TWO barriers per tile (proven protocol).

__global__ __launch_bounds__(256,2) void k_edge(
    const float* __restrict__ P, const float* __restrict__ Q,
    const float* __restrict__ pos, const float* __restrict__ dom,
    const int* __restrict__ offs, const int* __restrict__ csr,
    const float* __restrict__ Wpd, const float* __restrict__ W2, const float* __restrict__ b2,
    const float* __restrict__ invc, float* __restrict__ agg,
    float* __restrict__ zsum, float* __restrict__ zsumsq){
  __shared__ alignas(16) _Float16 w1pd[128*32];     // [f][k]: k0..2 Whi, k3..5 Whi, k6..8 Wlo, rest 0
  __shared__ alignas(16) _Float16 a1hi[16*136];     // block-shared [edge][f]
  __shared__ alignas(16) _Float16 a1lo[16*136];
  int tid = threadIdx.x;
  if (blockIdx.x==0 && tid<HD){ zsum[tid]=0.f; zsumsq[tid]=0.f; }
  if (tid < 128){
    int f = tid;
    #pragma unroll
    for (int k=0;k<32;++k) w1pd[f*32+k] = (_Float16)0.f;
    #pragma unroll
    for (int x=0;x<3;++x){
      float w = Wpd[x*HD + f];
      _Float16 h = (_Float16)w;
      w1pd[f*32 + x]     = h;
      w1pd[f*32 + 3 + x] = h;
      w1pd[f*32 + 6 + x] = (_Float16)(w - (float)h);
    }
  }
  int wid = tid>>6, lane = tid&63, g = lane>>4, c = lane&15;
  int t0 = 2*wid, t1 = 2*wid+1;
  half8 w2h[4][2], w2l[4][2];
  #pragma unroll
  for (int ks=0; ks<4; ++ks){
    #pragma unroll
    for (int tt=0; tt<2; ++tt){
      int col = 16*(2*wid+tt) + c;
      half8 fh, fl;
      #pragma unroll
      for (int j=0;j<8;++j){
        float w = W2[(ks*32 + g*8 + j)*HD + col];
        _Float16 h = (_Float16)w;
        fh[j] = h;
        fl[j] = (_Float16)(w - (float)h);
      }
      w2h[ks][tt] = fh;
      w2l[ks][tt] = fl;
    }
  }
  float b2v0 = b2[16*t0 + c], b2v1 = b2[16*t1 + c];
  float dm0=dom[0], dm1=dom[1], dm2=dom[2];
  f32x4 zero4 = {0.f,0.f,0.f,0.f};
  __syncthreads();
  int n0 = blockIdx.x*4;
  for (int n = n0; n < n0+4; ++n){
    f32x4 pv0 = *(const f32x4*)(P + (size_t)n*HD + 16*t0 + 4*g);
    f32x4 pv1 = *(const f32x4*)(P + (size_t)n*HD + 16*t1 + 4*g);
    float pn0=pos[n*3+0], pn1=pos[n*3+1], pn2=pos[n*3+2];
    float acc0=0.f, acc1=0.f;
    int ib=offs[n], ie=offs[n+1];
    for (int base=ib; base<ie; base+=16){
      int nb = ie - base; if (nb>16) nb = 16;
      int sA = csr[base + ((c<nb)? c : nb-1)];
      float q0=pos[sA*3+0], q1=pos[sA*3+1], q2=pos[sA*3+2];
      float pd0,pd1,pd2;
      { float diff,sh,ds;
        diff=pn0-q0; sh=(pn0<q0)?-dm0:dm0; ds=diff-sh; pd0=(fabsf(diff)<fabsf(ds))?diff:ds;
        diff=pn1-q1; sh=(pn1<q1)?-dm1:dm1; ds=diff-sh; pd1=(fabsf(diff)<fabsf(ds))?diff:ds;
        diff=pn2-q2; sh=(pn2<q2)?-dm2:dm2; ds=diff-sh; pd2=(fabsf(diff)<fabsf(ds))?diff:ds;
      }
      _Float16 p0h = (_Float16)pd0, p1h = (_Float16)pd1, p2h = (_Float16)pd2;
      _Float16 p0l = (_Float16)(pd0 - (float)p0h);
      _Float16 p1l = (_Float16)(pd1 - (float)p1h);
      _Float16 p2l = (_Float16)(pd2 - (float)p2h);
      half8 pdf;
      #pragma unroll
      for (int j=0;j<8;++j) pdf[j]=(_Float16)0.f;
      if (g==0){ pdf[0]=p0h; pdf[1]=p1h; pdf[2]=p2h; pdf[3]=p0l; pdf[4]=p1l; pdf[5]=p2l; pdf[6]=p0h; pdf[7]=p1h; }
      else if (g==1){ pdf[0]=p2h; }
      half8 w1f0 = *(const half8*)&w1pd[(16*t0 + c)*32 + g*8];
      half8 w1f1 = *(const half8*)&w1pd[(16*t1 + c)*32 + g*8];
      f32x4 d0 = __builtin_amdgcn_mfma_f32_16x16x32_f16(w1f0, pdf, zero4, 0,0,0);
      f32x4 d1 = __builtin_amdgcn_mfma_f32_16x16x32_f16(w1f1, pdf, zero4, 0,0,0);
      const float* Qs = Q + (size_t)sA*HD;
      f32x4 qv0 = *(const f32x4*)(Qs + 16*t0 + 4*g);
      f32x4 qv1 = *(const f32x4*)(Qs + 16*t1 + 4*g);
      half4v h0, l0, h1, l1;
      #pragma unroll
      for (int j=0;j<4;++j){
        float a = fmaxf(d0[j] + pv0[j] + qv0[j], 0.f);
        _Float16 hh = (_Float16)a;
        h0[j] = hh; l0[j] = (_Float16)(a - (float)hh);
        float b = fmaxf(d1[j] + pv1[j] + qv1[j], 0.f);
        _Float16 hb2 = (_Float16)b;
        h1[j] = hb2; l1[j] = (_Float16)(b - (float)hb2);
      }
      *(half4v*)&a1hi[c*136 + 16*t0 + 4*g] = h0;
      *(half4v*)&a1lo[c*136 + 16*t0 + 4*g] = l0;
      *(half4v*)&a1hi[c*136 + 16*t1 + 4*g] = h1;
      *(half4v*)&a1lo[c*136 + 16*t1 + 4*g] = l1;
      __syncthreads();
      f32x4 m0 = zero4, m1 = zero4;
      #pragma unroll
      for (int ks=0; ks<4; ++ks){
        half8 ah = *(const half8*)&a1hi[c*136 + ks*32 + g*8];
        half8 al = *(const half8*)&a1lo[c*136 + ks*32 + g*8];
        m0 = __builtin_amdgcn_mfma_f32_16x16x32_f16(ah, w2h[ks][0], m0, 0,0,0);
        m0 = __builtin_amdgcn_mfma_f32_16x16x32_f16(al, w2h[ks][0], m0, 0,0,0);
        m0 = __builtin_amdgcn_mfma_f32_16x16x32_f16(ah, w2l[ks][0], m0, 0,0,0);
        m1 = __builtin_amdgcn_mfma_f32_16x16x32_f16(ah, w2h[ks][1], m1, 0,0,0);
        m1 = __builtin_amdgcn_mfma_f32_16x16x32_f16(al, w2h[ks][1], m1, 0,0,0);
        m1 = __builtin_amdgcn_mfma_f32_16x16x32_f16(ah, w2l[ks][1], m1, 0,0,0);
      }
      if (nb == 16){
        acc0 += fmaxf(m0[0]+b2v0,0.f)+fmaxf(m0[1]+b2v0,0.f)+fmaxf(m0[2]+b2v0,0.f)+fmaxf(m0[3]+b2v0,0.f);
        acc1 += fmaxf(m1[0]+b2v1,0.f)+fmaxf(m1[1]+b2v1,0.f)+fmaxf(m1[2]+b2v1,0.f)+fmaxf(m1[3]+b2v1,0.f);
      } else {
        #pragma unroll
        for (int j=0;j<4;++j){
          if (4*g+j < nb){
            acc0 += fmaxf(m0[j]+b2v0, 0.f);
            acc1 += fmaxf(m1[j]+b2v1, 0.f);
          }
        }
      }
      __syncthreads();
    }
    acc0 += __shfl_xor(acc0, 16); acc0 += __shfl_xor(acc0, 32);
    acc1 += __shfl_xor(acc1, 16); acc1 += __shfl_xor(acc1, 32);
    if (g==0){
      float ic = invc[n];
      agg[n*HD + 16*t0 + c] = acc0*ic;
      agg[n*HD + 16*t1 + c] = acc1*ic;
    }
  }
}

// ---------------- update MLP via fp16-split MFMA ----------------
// 625 blocks x 512 threads; block = 16 nodes; wave w owns cols [16w,16w+16).
// X = [hn | agg] (K=256) staged hi/lo in LDS; U1/U2 B-frags in registers.
// GEMM1 (8 k-slots) -> relu+bias -> a1 LDS -> GEMM2 (4 k-slots) -> residual+stats.

__global__ __launch_bounds__(512,1) void k_upd(
    float* __restrict__ hb, const float* __restrict__ mu, const float* __restrict__ rstd,
    const float* __restrict__ agg,
    const float* __restrict__ U1, const float* __restrict__ b1e,
    const float* __restrict__ U2, const float* __restrict__ bs2,
    float* __restrict__ sum, float* __restrict__ sumsq){
  __shared__ alignas(16) _Float16 Xhi[16*264];
  __shared__ alignas(16) _Float16 Xlo[16*264];
  __shared__ alignas(16) _Float16 Ahi[16*136];
  __shared__ alignas(16) _Float16 Alo[16*136];
  int tid = threadIdx.x;
  int n0 = blockIdx.x*16;
  // ---- stage X = [hn | agg], fp16 split: thread t -> node t>>5, feats (t&31)*8..+8 ----
  {
    int node = tid>>5, chunk = tid&31;
    int n = n0 + node;
    int f = chunk*8;
    half8 xh, xl;
    if (f < 128){
      #pragma unroll
      for (int j=0;j<8;++j){
        float x = (hb[(size_t)n*HD + f+j] - mu[f+j]) * rstd[f+j];
        _Float16 h = (_Float16)x;
        xh[j] = h; xl[j] = (_Float16)(x - (float)h);
      }
    } else {
      #pragma unroll
      for (int j=0;j<8;++j){
        float x = agg[(size_t)n*HD + (f-128)+j];
        _Float16 h = (_Float16)x;
        xh[j] = h; xl[j] = (_Float16)(x - (float)h);
      }
    }
    *(half8*)&Xhi[node*264 + f] = xh;
    *(half8*)&Xlo[node*264 + f] = xl;
  }
  int wid = tid>>6, lane = tid&63, g = lane>>4, c = lane&15;
  int col = 16*wid + c;
  // B-frags (verified k_edge pattern): B[k = ks*32 + g*8 + j][col]
  half8 b1h[8], b1l[8], b2h[4], b2l[4];
  #pragma unroll
  for (int ks=0; ks<8; ++ks){
    half8 fh, fl;
    #pragma unroll
    for (int j=0;j<8;++j){
      float w = U1[(size_t)(ks*32 + g*8 + j)*HD + col];
      _Float16 h = (_Float16)w;
      fh[j]=h; fl[j]=(_Float16)(w - (float)h);
    }
    b1h[ks]=fh; b1l[ks]=fl;
  }
  #pragma unroll
  for (int ks=0; ks<4; ++ks){
    half8 fh, fl;
    #pragma unroll
    for (int j=0;j<8;++j){
      float w = U2[(size_t)(ks*32 + g*8 + j)*HD + col];
      _Float16 h = (_Float16)w;
      fh[j]=h; fl[j]=(_Float16)(w - (float)h);
    }
    b2h[ks]=fh; b2l[ks]=fl;
  }
  f32x4 zero4 = {0.f,0.f,0.f,0.f};
  __syncthreads();
  // ---- GEMM1: z[node][col], A rows = node (c), K = 256 ----
  f32x4 d = zero4;
  #pragma unroll
  for (int ks=0; ks<8; ++ks){
    half8 ah = *(const half8*)&Xhi[c*264 + ks*32 + g*8];
    half8 al = *(const half8*)&Xlo[c*264 + ks*32 + g*8];
    d = __builtin_amdgcn_mfma_f32_16x16x32_f16(ah, b1h[ks], d, 0,0,0);
    d = __builtin_amdgcn_mfma_f32_16x16x32_f16(al, b1h[ks], d, 0,0,0);
    d = __builtin_amdgcn_mfma_f32_16x16x32_f16(ah, b1l[ks], d, 0,0,0);
  }
  // a1 = relu(z + b1e[col]) -> LDS [row][col]; D rows = g*4+jj
  {
    float bb = b1e[col];
    #pragma unroll
    for (int jj=0;jj<4;++jj){
      float a = fmaxf(d[jj] + bb, 0.f);
      _Float16 h = (_Float16)a;
      Ahi[(g*4+jj)*136 + col] = h;
      Alo[(g*4+jj)*136 + col] = (_Float16)(a - (float)h);
    }
  }
  __syncthreads();
  // ---- GEMM2: u[node][col], K = 128 ----
  f32x4 u = zero4;
  #pragma unroll
  for (int ks=0; ks<4; ++ks){
    half8 ah = *(const half8*)&Ahi[c*136 + ks*32 + g*8];
    half8 al = *(const half8*)&Alo[c*136 + ks*32 + g*8];
    u = __builtin_amdgcn_mfma_f32_16x16x32_f16(ah, b2h[ks], u, 0,0,0);
    u = __builtin_amdgcn_mfma_f32_16x16x32_f16(al, b2h[ks], u, 0,0,0);
    u = __builtin_amdgcn_mfma_f32_16x16x32_f16(ah, b2l[ks], u, 0,0,0);
  }
  // ---- epilogue: hb_new = hn + relu(u + bs2); stats ----
  float bc = bs2[col];
  float mc = mu[col], rc = rstd[col];
  float s=0.f, q=0.f;
  #pragma unroll
  for (int jj=0;jj<4;++jj){
    int n = n0 + g*4 + jj;
    float hn = (hb[(size_t)n*HD + col] - mc)*rc;
    float b0 = hn + fmaxf(u[jj] + bc, 0.f);
    hb[(size_t)n*HD + col] = b0;
    s += b0; q += b0*b0;
  }
  s += __shfl_xor(s,16); s += __shfl_xor(s,32);
  q += __shfl_xor(q,16); q += __shfl_xor(q,32);
  if (g==0){
    atomicAdd(&sum[col], s);
    atomicAdd(&sumsq[col], q);
  }
}

__global__ void k_normfin(const float* __restrict__ sum, const float* __restrict__ sumsq,
                          float* __restrict__ mu, float* __restrict__ rstd){
  int t=threadIdx.x;
  float m = sum[t]*(1.0f/NN);
  float var = sumsq[t]*(1.0f/NN) - m*m;
  mu[t]=m;
  rstd[t]=rsqrtf(fmaxf(var,0.0f)+EPSV);
}

// ---------------- decoder + outputs ----------------

__global__ void k_out(const float* __restrict__ hb, const float* __restrict__ mu, const float* __restrict__ rstd,
                      const float* __restrict__ pos, const float* __restrict__ v,
                      const float* __restrict__ W1, const float* __restrict__ b1,
                      const float* __restrict__ W2, const float* __restrict__ b2,
                      const float* __restrict__ domn, float* __restrict__ out){
  __shared__ alignas(16) float hs[4][HD*4];
  __shared__ alignas(16) float a1s[4][HD*4];
  int tid=threadIdx.x, wid=tid>>6, lane=tid&63;
  int gw=blockIdx.x*4+wid;
  int f0=lane, f1=lane+64;
  float* h4=hs[wid];
  float* a1p=a1s[wid];
  int n0=gw*4;
  float mu0=mu[f0], mu1=mu[f1], rs0=rstd[f0], rs1=rstd[f1];
  float4 hv0,hv1;
  hv0.x=(hb[(n0+0)*HD+f0]-mu0)*rs0; hv0.y=(hb[(n0+1)*HD+f0]-mu0)*rs0;
  hv0.z=(hb[(n0+2)*HD+f0]-mu0)*rs0; hv0.w=(hb[(n0+3)*HD+f0]-mu0)*rs0;
  hv1.x=(hb[(n0+0)*HD+f1]-mu1)*rs1; hv1.y=(hb[(n0+1)*HD+f1]-mu1)*rs1;
  hv1.z=(hb[(n0+2)*HD+f1]-mu1)*rs1; hv1.w=(hb[(n0+3)*HD+f1]-mu1)*rs1;
  *(float4*)&h4[f0*4]=hv0; *(float4*)&h4[f1*4]=hv1;
  float b1f0=b1[f0], b1f1=b1[f1];
  float zf0[4]={b1f0,b1f0,b1f0,b1f0}, zf1[4]={b1f1,b1f1,b1f1,b1f1};
  for (int k=0;k<HD;++k){
    float4 a = *(const float4*)&h4[k*4];
    float w0=W1[k*HD+f0], w1=W1[k*HD+f1];
    zf0[0]+=a.x*w0; zf1[0]+=a.x*w1;
    zf0[1]+=a.y*w0; zf1[1]+=a.y*w1;
    zf0[2]+=a.z*w0; zf1[2]+=a.z*w1;
    zf0[3]+=a.w*w0; zf1[3]+=a.w*w1;
  }
  *(float4*)&a1p[f0*4] = make_float4(relu_(zf0[0]),relu_(zf0[1]),relu_(zf0[2]),relu_(zf0[3]));
  *(float4*)&a1p[f1*4] = make_float4(relu_(zf1[0]),relu_(zf1[1]),relu_(zf1[2]),relu_(zf1[3]));
  if (lane < 36){
    int e = lane/9, j = lane - e*9;
    int n = n0+e;
    float p = b2[j];
    for (int k=0;k<HD;++k) p += a1p[k*4+e]*W2[k*9+j];
    if (j<3){
      p += pos[n*3+j];
      float d = domn[j];
      p = p - floorf(p/d)*d;
      out[n*3+j] = p;
    } else {
      p += v[n*6 + (j-3)];
      out[3*NN + n*6 + (j-3)] = p;
    }
  }
}

__global__ void k_macro(const float* __restrict__ sum, const float* __restrict__ mu, const float* __restrict__ rstd,
                        const float* __restrict__ W1, const float* __restrict__ b1,
                        const float* __restrict__ W2, const float* __restrict__ b2,
                        float* __restrict__ out){
  __shared__ float hm[HD];
  __shared__ float as[HD];
  int t=threadIdx.x;
  hm[t] = (sum[t]*(1.0f/NN) - mu[t])*rstd[t];
  __syncthreads();
  float z=b1[t];
  for (int k=0;k<HD;++k) z += hm[k]*W1[k*HD+t];
  as[t]=relu_(z);
  __syncthreads();
  if (t<3){
    float p=b2[t];
    for (int k=0;k<HD;++k) p += as[k]*W2[k*3+t];
    out[9*NN+t]=p;
  }
}

// ---------------- host launch ----------------

extern "C" void kernel_launch(void* const* d_in, const int* in_sizes, int n_in,
                              void* d_out, int out_size, void* d_ws, size_t ws_size,
                              hipStream_t stream) {
  const float* v    = (const float*)d_in[0];
  const float* pos  = (const float*)d_in[1];
  const float* r    = (const float*)d_in[2];
  const float* dom  = (const float*)d_in[3];
  const float* tt   = (const float*)d_in[4];
  const float* xg   = (const float*)d_in[5];
  const float* domn = (const float*)d_in[6];
  const float* tn   = (const float*)d_in[7];
  const int*   eidx = (const int*)d_in[8];
  const float* embW1 = (const float*)d_in[10];
  const float* embB1 = (const float*)d_in[11];
  const float* embW2 = (const float*)d_in[12];
  const float* embB2 = (const float*)d_in[13];
  const float* msgW1 = (const float*)d_in[14];
  const float* msgB1 = (const float*)d_in[15];
  const float* msgW2 = (const float*)d_in[16];
  const float* msgB2 = (const float*)d_in[17];
  const float* updW1 = (const float*)d_in[18];
  const float* updB1 = (const float*)d_in[19];
  const float* updW2 = (const float*)d_in[20];
  const float* updB2 = (const float*)d_in[21];
  const float* outW1 = (const float*)d_in[22];
  const float* outB1 = (const float*)d_in[23];
  const float* outW2 = (const float*)d_in[24];
  const float* outB2 = (const float*)d_in[25];
  const float* macW1 = (const float*)d_in[26];
  const float* macB1 = (const float*)d_in[27];
  const float* macW2 = (const float*)d_in[28];
  const float* macB2 = (const float*)d_in[29];
  float* out = (float*)d_out;
  float* ws  = (float*)d_ws;

  float* hb    = ws;
  float* P     = ws + 1280000;
  float* Q     = ws + 2560000;
  float* agg   = ws + 3840000;
  float* invc  = ws + 5120000;
  float* b1eff = ws + 5130000;   // 13*128
  float* sum   = ws + 5131664;
  float* sumsq = ws + 5131792;
  float* mu    = ws + 5131920;
  float* rstd  = ws + 5132048;
  int* counts  = (int*)(ws + 5132304);
  int* offs    = counts + NN;       // NN+1
  int* cursor  = offs + NN + 1;
  int* csr     = cursor + NN;       // NE

  const int* srcA = eidx;
  const int* dstA = eidx + NE;

  hipMemsetAsync(counts, 0, NN*sizeof(int), stream);
  hipMemsetAsync(cursor, 0, NN*sizeof(int), stream);

  k_degree<<<(NE+255)/256, 256, 0, stream>>>(dstA, counts);
  k_scan<<<1, 1024, 0, stream>>>(counts, offs, invc);
  k_place<<<(NE+255)/256, 256, 0, stream>>>(srcA, dstA, offs, cursor, csr);
  k_biasfold<<<14, 128, 0, stream>>>(dom, tt, xg, domn, tn, embW1, embB1, msgW1, msgB1, updW1, updB1,
                                     b1eff, mu, rstd);
  k_embed<<<625, 256, 0, stream>>>(r, v, embW1, b1eff, embW2, embB2, hb);

  for (int l=0; l<NL; ++l){
    k_hW<<<625,256,0,stream>>>(hb, mu, rstd, v, r, msgW1 + (size_t)l*157*HD, b1eff + (1+l)*HD, P, Q);
    k_edge<<<2500,256,0,stream>>>(P, Q, pos, dom, offs, csr,
        msgW1 + ((size_t)l*157+142)*HD,
        msgW2 + (size_t)l*HD*HD, msgB2 + l*HD, invc, agg, sum, sumsq);
    k_upd<<<625,512,0,stream>>>(hb, mu, rstd, agg,
        updW1 + (size_t)l*268*HD, b1eff + (7+l)*HD,
        updW2 + (size_t)l*HD*HD, updB2 + l*HD, sum, sumsq);
    k_normfin<<<1,128,0,stream>>>(sum, sumsq, mu, rstd);
  }

  k_out<<<625,256,0,stream>>>(hb, mu, rstd, pos, v, outW1, outB1, outW2, outB2, domn, out);
  k_macro<<<1,128,0,stream>>>(sum, mu, rstd, macW1, macB1, macW2, macB2, out);
}

// Round 13
// 855.642 us; speedup vs baseline: 1.6207x; 1.0242x over previous
//
#include <hip/hip_runtime.h>
#include <hip/hip_bf16.h>

#define NN 10000
#define NE 320000
#define HD 128
#define NL 6
#define EPSV 1e-5f

typedef _Float16 half8  __attribute__((ext_vector_type(8)));
typedef _Float16 half4v __attribute__((ext_vector_type(4)));
typedef float    f32x4  __attribute__((ext_vector_type(4)));

__device__ __forceinline__ float relu_(float x){ return fmaxf(x, 0.0f); }

// ---------------- degree / scan / place (CSR build) ----------------

__global__ void k_degree(const int* __restrict__ dst, int* __restrict__ counts){
  int e = blockIdx.x*256 + threadIdx.x;
  if (e < NE) atomicAdd(&counts[dst[e]], 1);
}

__global__ void k_scan(const int* __restrict__ counts, int* __restrict__ offs, float* __restrict__ invc){
  __shared__ int lds[1024];
  __shared__ int base_s;
  int tid = threadIdx.x;
  if (tid==0) base_s = 0;
  __syncthreads();
  for (int start=0; start<NN; start+=1024){
    int i = start+tid;
    int vv = (i<NN)? counts[i] : 0;
    lds[tid]=vv; __syncthreads();
    for (int off=1; off<1024; off<<=1){
      int t = (tid>=off)? lds[tid-off] : 0;
      __syncthreads();
      lds[tid] += t;
      __syncthreads();
    }
    int incl = lds[tid];
    if (i<NN){
      offs[i] = base_s + incl - vv;
      invc[i] = 1.0f / fmaxf((float)vv, 1.0f);
    }
    __syncthreads();
    if (tid==1023) base_s += lds[1023];
    __syncthreads();
  }
  if (tid==0) offs[NN] = base_s;
}

__global__ void k_place(const int* __restrict__ src, const int* __restrict__ dst,
                        const int* __restrict__ offs, int* __restrict__ cursor, int* __restrict__ csr){
  int e = blockIdx.x*256 + threadIdx.x;
  if (e < NE){
    int d = dst[e];
    int p = atomicAdd(&cursor[d], 1);
    csr[offs[d]+p] = src[e];
  }
}

// ---------------- fold gf into first-layer biases + init mu/rstd ----------------

__global__ void k_biasfold(const float* __restrict__ dom, const float* __restrict__ tt,
                           const float* __restrict__ xg, const float* __restrict__ domn,
                           const float* __restrict__ tn,
                           const float* __restrict__ embW1, const float* __restrict__ embB1,
                           const float* __restrict__ msgW1, const float* __restrict__ msgB1,
                           const float* __restrict__ updW1, const float* __restrict__ updB1,
                           float* __restrict__ b1eff, float* __restrict__ mu, float* __restrict__ rstd){
  float gf[12];
  gf[0]=dom[0]; gf[1]=dom[1]; gf[2]=dom[2]; gf[3]=tt[0];
  gf[4]=xg[0]; gf[5]=xg[1]; gf[6]=xg[2]; gf[7]=xg[3];
  gf[8]=domn[0]; gf[9]=domn[1]; gf[10]=domn[2]; gf[11]=tn[0];
  int b = blockIdx.x, t = threadIdx.x;
  if (b==0){
    float s = embB1[t];
    #pragma unroll
    for (int k=0;k<12;++k) s += gf[k]*embW1[(7+k)*HD + t];
    b1eff[t] = s;
  } else if (b<=6){
    int l=b-1;
    float s = msgB1[l*HD+t];
    #pragma unroll
    for (int k=0;k<12;++k) s += gf[k]*msgW1[((size_t)l*157 + 145+k)*HD + t];
    b1eff[(1+l)*HD + t] = s;
  } else if (b<=12){
    int l=b-7;
    float s = updB1[l*HD+t];
    #pragma unroll
    for (int k=0;k<12;++k) s += gf[k]*updW1[((size_t)l*268 + 256+k)*HD + t];
    b1eff[(7+l)*HD + t] = s;
  } else {
    mu[t] = 0.f;
    rstd[t] = 1.f;
  }
}

// ---------------- embedding: hb = mlp2_relu([r,v,gf]) ----------------

__global__ void k_embed(const float* __restrict__ r, const float* __restrict__ v,
                        const float* __restrict__ W1, const float* __restrict__ b1e,
                        const float* __restrict__ W2, const float* __restrict__ b2,
                        float* __restrict__ hb){
  __shared__ alignas(16) float a1s[4][HD];
  int tid=threadIdx.x, wid=tid>>6, lane=tid&63;
  int gw = blockIdx.x*4 + wid;
  int f0=lane, f1=lane+64;
  float* a1 = a1s[wid];
  float b1f0=b1e[f0], b1f1=b1e[f1], b2f0=b2[f0], b2f1=b2[f1];
  for (int n=gw*4; n<gw*4+4; ++n){
    float in7[7];
    in7[0]=r[n];
    #pragma unroll
    for (int k=0;k<6;++k) in7[1+k]=v[n*6+k];
    float z0=b1f0, z1=b1f1;
    #pragma unroll
    for (int k=0;k<7;++k){ z0 += in7[k]*W1[k*HD+f0]; z1 += in7[k]*W1[k*HD+f1]; }
    a1[f0]=relu_(z0); a1[f1]=relu_(z1);
    float h0=b2f0, h1=b2f1;
    for (int k=0;k<HD;++k){ float a=a1[k]; h0+=a*W2[k*HD+f0]; h1+=a*W2[k*HD+f1]; }
    hb[n*HD+f0]=relu_(h0); hb[n*HD+f1]=relu_(h1);
  }
}

// ---------------- P/Q via fp16-split MFMA (k_upd template) ----------------
// 625 blocks x 512 threads; block = 16 nodes; wave w owns cols [16w,16w+16).
// M = hn @ W[0:128]  (K=128, 3-term fp16 split, X staged hi/lo in LDS)
// P[n][col] = M + b1eff[col] + sum_x v[n,x]*W[128+x][col] + r[n]*W[140][col]
// Q[n][col] = -M           + sum_x v[n,x]*W[134+x][col] + r[n]*W[141][col]

__global__ __launch_bounds__(512,1) void k_hW(
    const float* __restrict__ hb, const float* __restrict__ mu, const float* __restrict__ rstd,
    const float* __restrict__ v, const float* __restrict__ r,
    const float* __restrict__ W, const float* __restrict__ b1e,
    float* __restrict__ P, float* __restrict__ Q){
  __shared__ alignas(16) _Float16 Xhi[16*136];
  __shared__ alignas(16) _Float16 Xlo[16*136];
  int tid = threadIdx.x;
  int n0 = blockIdx.x*16;
  if (tid < 256){
    int node = tid>>4, chunk = tid&15;
    int n = n0 + node;
    int f = chunk*8;
    half8 xh, xl;
    #pragma unroll
    for (int j=0;j<8;++j){
      float x = (hb[(size_t)n*HD + f+j] - mu[f+j]) * rstd[f+j];
      _Float16 h = (_Float16)x;
      xh[j] = h; xl[j] = (_Float16)(x - (float)h);
    }
    *(half8*)&Xhi[node*136 + f] = xh;
    *(half8*)&Xlo[node*136 + f] = xl;
  }
  int wid = tid>>6, lane = tid&63, g = lane>>4, c = lane&15;
  int col = 16*wid + c;
  // B-frags (verified k_upd pattern): B[k = ks*32 + g*8 + j][col]
  half8 bh[4], bl[4];
  #pragma unroll
  for (int ks=0; ks<4; ++ks){
    half8 fh, fl;
    #pragma unroll
    for (int j=0;j<8;++j){
      float w = W[(size_t)(ks*32 + g*8 + j)*HD + col];
      _Float16 h = (_Float16)w;
      fh[j]=h; fl[j]=(_Float16)(w - (float)h);
    }
    bh[ks]=fh; bl[ks]=fl;
  }
  float wvi[6], wvj[6];
  #pragma unroll
  for (int x=0;x<6;++x){
    wvi[x]=W[(size_t)(128+x)*HD+col];
    wvj[x]=W[(size_t)(134+x)*HD+col];
  }
  float wri=W[(size_t)140*HD+col], wrj=W[(size_t)141*HD+col];
  float b1c=b1e[col];
  f32x4 zero4 = {0.f,0.f,0.f,0.f};
  __syncthreads();
  f32x4 d = zero4;
  #pragma unroll
  for (int ks=0; ks<4; ++ks){
    half8 ah = *(const half8*)&Xhi[c*136 + ks*32 + g*8];
    half8 al = *(const half8*)&Xlo[c*136 + ks*32 + g*8];
    d = __builtin_amdgcn_mfma_f32_16x16x32_f16(ah, bh[ks], d, 0,0,0);
    d = __builtin_amdgcn_mfma_f32_16x16x32_f16(al, bh[ks], d, 0,0,0);
    d = __builtin_amdgcn_mfma_f32_16x16x32_f16(ah, bl[ks], d, 0,0,0);
  }
  #pragma unroll
  for (int jj=0;jj<4;++jj){
    int n = n0 + g*4 + jj;
    float m = d[jj];
    float p = m + b1c, q = -m;
    #pragma unroll
    for (int x=0;x<6;++x){
      float vx = v[n*6+x];
      p += vx*wvi[x]; q += vx*wvj[x];
    }
    float rn = r[n];
    p += rn*wri; q += rn*wrj;
    P[(size_t)n*HD+col]=p;
    Q[(size_t)n*HD+col]=q;
  }
}

// ---------------- edge MLP via fp16-split MFMA, wave-cooperative ----------------
// 2500 blocks x 4 dst nodes. Single a1 buffer, TWO barriers per tile (proven protocol).
// w1pd row stride padded 32->40 halfs (80B = 20 dwords -> 2-way bank aliasing, free).

__global__ __launch_bounds__(256,2) void k_edge(
    const float* __restrict__ P, const float* __restrict__ Q,
    const float* __restrict__ pos, const float* __restrict__ dom,
    const int* __restrict__ offs, const int* __restrict__ csr,
    const float* __restrict__ Wpd, const float* __restrict__ W2, const float* __restrict__ b2,
    const float* __restrict__ invc, float* __restrict__ agg,
    float* __restrict__ zsum, float* __restrict__ zsumsq){
  __shared__ alignas(16) _Float16 w1pd[128*40];     // [f][k]: k0..2 Whi, k3..5 Whi, k6..8 Wlo, rest 0; stride 40
  __shared__ alignas(16) _Float16 a1hi[16*136];     // block-shared [edge][f]
  __shared__ alignas(16) _Float16 a1lo[16*136];
  int tid = threadIdx.x;
  if (blockIdx.x==0 && tid<HD){ zsum[tid]=0.f; zsumsq[tid]=0.f; }
  if (tid < 128){
    int f = tid;
    #pragma unroll
    for (int k=0;k<32;++k) w1pd[f*40+k] = (_Float16)0.f;
    #pragma unroll
    for (int x=0;x<3;++x){
      float w = Wpd[x*HD + f];
      _Float16 h = (_Float16)w;
      w1pd[f*40 + x]     = h;
      w1pd[f*40 + 3 + x] = h;
      w1pd[f*40 + 6 + x] = (_Float16)(w - (float)h);
    }
  }
  int wid = tid>>6, lane = tid&63, g = lane>>4, c = lane&15;
  int t0 = 2*wid, t1 = 2*wid+1;
  half8 w2h[4][2], w2l[4][2];
  #pragma unroll
  for (int ks=0; ks<4; ++ks){
    #pragma unroll
    for (int tt=0; tt<2; ++tt){
      int col = 16*(2*wid+tt) + c;
      half8 fh, fl;
      #pragma unroll
      for (int j=0;j<8;++j){
        float w = W2[(ks*32 + g*8 + j)*HD + col];
        _Float16 h = (_Float16)w;
        fh[j] = h;
        fl[j] = (_Float16)(w - (float)h);
      }
      w2h[ks][tt] = fh;
      w2l[ks][tt] = fl;
    }
  }
  float b2v0 = b2[16*t0 + c], b2v1 = b2[16*t1 + c];
  float dm0=dom[0], dm1=dom[1], dm2=dom[2];
  f32x4 zero4 = {0.f,0.f,0.f,0.f};
  __syncthreads();
  int n0 = blockIdx.x*4;
  for (int n = n0; n < n0+4; ++n){
    f32x4 pv0 = *(const f32x4*)(P + (size_t)n*HD + 16*t0 + 4*g);
    f32x4 pv1 = *(const f32x4*)(P + (size_t)n*HD + 16*t1 + 4*g);
    float pn0=pos[n*3+0], pn1=pos[n*3+1], pn2=pos[n*3+2];
    float acc0=0.f, acc1=0.f;
    int ib=offs[n], ie=offs[n+1];
    for (int base=ib; base<ie; base+=16){
      int nb = ie - base; if (nb>16) nb = 16;
      int sA = csr[base + ((c<nb)? c : nb-1)];
      float q0=pos[sA*3+0], q1=pos[sA*3+1], q2=pos[sA*3+2];
      float pd0,pd1,pd2;
      { float diff,sh,ds;
        diff=pn0-q0; sh=(pn0<q0)?-dm0:dm0; ds=diff-sh; pd0=(fabsf(diff)<fabsf(ds))?diff:ds;
        diff=pn1-q1; sh=(pn1<q1)?-dm1:dm1; ds=diff-sh; pd1=(fabsf(diff)<fabsf(ds))?diff:ds;
        diff=pn2-q2; sh=(pn2<q2)?-dm2:dm2; ds=diff-sh; pd2=(fabsf(diff)<fabsf(ds))?diff:ds;
      }
      _Float16 p0h = (_Float16)pd0, p1h = (_Float16)pd1, p2h = (_Float16)pd2;
      _Float16 p0l = (_Float16)(pd0 - (float)p0h);
      _Float16 p1l = (_Float16)(pd1 - (float)p1h);
      _Float16 p2l = (_Float16)(pd2 - (float)p2h);
      half8 pdf;
      #pragma unroll
      for (int j=0;j<8;++j) pdf[j]=(_Float16)0.f;
      if (g==0){ pdf[0]=p0h; pdf[1]=p1h; pdf[2]=p2h; pdf[3]=p0l; pdf[4]=p1l; pdf[5]=p2l; pdf[6]=p0h; pdf[7]=p1h; }
      else if (g==1){ pdf[0]=p2h; }
      half8 w1f0 = *(const half8*)&w1pd[(16*t0 + c)*40 + g*8];
      half8 w1f1 = *(const half8*)&w1pd[(16*t1 + c)*40 + g*8];
      f32x4 d0 = __builtin_amdgcn_mfma_f32_16x16x32_f16(w1f0, pdf, zero4, 0,0,0);
      f32x4 d1 = __builtin_amdgcn_mfma_f32_16x16x32_f16(w1f1, pdf, zero4, 0,0,0);
      const float* Qs = Q + (size_t)sA*HD;
      f32x4 qv0 = *(const f32x4*)(Qs + 16*t0 + 4*g);
      f32x4 qv1 = *(const f32x4*)(Qs + 16*t1 + 4*g);
      half4v h0, l0, h1, l1;
      #pragma unroll
      for (int j=0;j<4;++j){
        float a = fmaxf(d0[j] + pv0[j] + qv0[j], 0.f);
        _Float16 hh = (_Float16)a;
        h0[j] = hh; l0[j] = (_Float16)(a - (float)hh);
        float b = fmaxf(d1[j] + pv1[j] + qv1[j], 0.f);
        _Float16 hb2 = (_Float16)b;
        h1[j] = hb2; l1[j] = (_Float16)(b - (float)hb2);
      }
      *(half4v*)&a1hi[c*136 + 16*t0 + 4*g] = h0;
      *(half4v*)&a1lo[c*136 + 16*t0 + 4*g] = l0;
      *(half4v*)&a1hi[c*136 + 16*t1 + 4*g] = h1;
      *(half4v*)&a1lo[c*136 + 16*t1 + 4*g] = l1;
      __syncthreads();
      f32x4 m0 = zero4, m1 = zero4;
      #pragma unroll
      for (int ks=0; ks<4; ++ks){
        half8 ah = *(const half8*)&a1hi[c*136 + ks*32 + g*8];
        half8 al = *(const half8*)&a1lo[c*136 + ks*32 + g*8];
        m0 = __builtin_amdgcn_mfma_f32_16x16x32_f16(ah, w2h[ks][0], m0, 0,0,0);
        m0 = __builtin_amdgcn_mfma_f32_16x16x32_f16(al, w2h[ks][0], m0, 0,0,0);
        m0 = __builtin_amdgcn_mfma_f32_16x16x32_f16(ah, w2l[ks][0], m0, 0,0,0);
        m1 = __builtin_amdgcn_mfma_f32_16x16x32_f16(ah, w2h[ks][1], m1, 0,0,0);
        m1 = __builtin_amdgcn_mfma_f32_16x16x32_f16(al, w2h[ks][1], m1, 0,0,0);
        m1 = __builtin_amdgcn_mfma_f32_16x16x32_f16(ah, w2l[ks][1], m1, 0,0,0);
      }
      if (nb == 16){
        acc0 += fmaxf(m0[0]+b2v0,0.f)+fmaxf(m0[1]+b2v0,0.f)+fmaxf(m0[2]+b2v0,0.f)+fmaxf(m0[3]+b2v0,0.f);
        acc1 += fmaxf(m1[0]+b2v1,0.f)+fmaxf(m1[1]+b2v1,0.f)+fmaxf(m1[2]+b2v1,0.f)+fmaxf(m1[3]+b2v1,0.f);
      } else {
        #pragma unroll
        for (int j=0;j<4;++j){
          if (4*g+j < nb){
            acc0 += fmaxf(m0[j]+b2v0, 0.f);
            acc1 += fmaxf(m1[j]+b2v1, 0.f);
          }
        }
      }
      __syncthreads();
    }
    acc0 += __shfl_xor(acc0, 16); acc0 += __shfl_xor(acc0, 32);
    acc1 += __shfl_xor(acc1, 16); acc1 += __shfl_xor(acc1, 32);
    if (g==0){
      float ic = invc[n];
      agg[n*HD + 16*t0 + c] = acc0*ic;
      agg[n*HD + 16*t1 + c] = acc1*ic;
    }
  }
}

// ---------------- update MLP via fp16-split MFMA ----------------
// 625 blocks x 512 threads; block = 16 nodes; wave w owns cols [16w,16w+16).

__global__ __launch_bounds__(512,1) void k_upd(
    float* __restrict__ hb, const float* __restrict__ mu, const float* __restrict__ rstd,
    const float* __restrict__ agg,
    const float* __restrict__ U1, const float* __restrict__ b1e,
    const float* __restrict__ U2, const float* __restrict__ bs2,
    float* __restrict__ sum, float* __restrict__ sumsq){
  __shared__ alignas(16) _Float16 Xhi[16*264];
  __shared__ alignas(16) _Float16 Xlo[16*264];
  __shared__ alignas(16) _Float16 Ahi[16*136];
  __shared__ alignas(16) _Float16 Alo[16*136];
  int tid = threadIdx.x;
  int n0 = blockIdx.x*16;
  {
    int node = tid>>5, chunk = tid&31;
    int n = n0 + node;
    int f = chunk*8;
    half8 xh, xl;
    if (f < 128){
      #pragma unroll
      for (int j=0;j<8;++j){
        float x = (hb[(size_t)n*HD + f+j] - mu[f+j]) * rstd[f+j];
        _Float16 h = (_Float16)x;
        xh[j] = h; xl[j] = (_Float16)(x - (float)h);
      }
    } else {
      #pragma unroll
      for (int j=0;j<8;++j){
        float x = agg[(size_t)n*HD + (f-128)+j];
        _Float16 h = (_Float16)x;
        xh[j] = h; xl[j] = (_Float16)(x - (float)h);
      }
    }
    *(half8*)&Xhi[node*264 + f] = xh;
    *(half8*)&Xlo[node*264 + f] = xl;
  }
  int wid = tid>>6, lane = tid&63, g = lane>>4, c = lane&15;
  int col = 16*wid + c;
  half8 b1h[8], b1l[8], b2h[4], b2l[4];
  #pragma unroll
  for (int ks=0; ks<8; ++ks){
    half8 fh, fl;
    #pragma unroll
    for (int j=0;j<8;++j){
      float w = U1[(size_t)(ks*32 + g*8 + j)*HD + col];
      _Float16 h = (_Float16)w;
      fh[j]=h; fl[j]=(_Float16)(w - (float)h);
    }
    b1h[ks]=fh; b1l[ks]=fl;
  }
  #pragma unroll
  for (int ks=0; ks<4; ++ks){
    half8 fh, fl;
    #pragma unroll
    for (int j=0;j<8;++j){
      float w = U2[(size_t)(ks*32 + g*8 + j)*HD + col];
      _Float16 h = (_Float16)w;
      fh[j]=h; fl[j]=(_Float16)(w - (float)h);
    }
    b2h[ks]=fh; b2l[ks]=fl;
  }
  f32x4 zero4 = {0.f,0.f,0.f,0.f};
  __syncthreads();
  f32x4 d = zero4;
  #pragma unroll
  for (int ks=0; ks<8; ++ks){
    half8 ah = *(const half8*)&Xhi[c*264 + ks*32 + g*8];
    half8 al = *(const half8*)&Xlo[c*264 + ks*32 + g*8];
    d = __builtin_amdgcn_mfma_f32_16x16x32_f16(ah, b1h[ks], d, 0,0,0);
    d = __builtin_amdgcn_mfma_f32_16x16x32_f16(al, b1h[ks], d, 0,0,0);
    d = __builtin_amdgcn_mfma_f32_16x16x32_f16(ah, b1l[ks], d, 0,0,0);
  }
  {
    float bb = b1e[col];
    #pragma unroll
    for (int jj=0;jj<4;++jj){
      float a = fmaxf(d[jj] + bb, 0.f);
      _Float16 h = (_Float16)a;
      Ahi[(g*4+jj)*136 + col] = h;
      Alo[(g*4+jj)*136 + col] = (_Float16)(a - (float)h);
    }
  }
  __syncthreads();
  f32x4 u = zero4;
  #pragma unroll
  for (int ks=0; ks<4; ++ks){
    half8 ah = *(const half8*)&Ahi[c*136 + ks*32 + g*8];
    half8 al = *(const half8*)&Alo[c*136 + ks*32 + g*8];
    u = __builtin_amdgcn_mfma_f32_16x16x32_f16(ah, b2h[ks], u, 0,0,0);
    u = __builtin_amdgcn_mfma_f32_16x16x32_f16(al, b2h[ks], u, 0,0,0);
    u = __builtin_amdgcn_mfma_f32_16x16x32_f16(ah, b2l[ks], u, 0,0,0);
  }
  float bc = bs2[col];
  float mc = mu[col], rc = rstd[col];
  float s=0.f, q=0.f;
  #pragma unroll
  for (int jj=0;jj<4;++jj){
    int n = n0 + g*4 + jj;
    float hn = (hb[(size_t)n*HD + col] - mc)*rc;
    float b0 = hn + fmaxf(u[jj] + bc, 0.f);
    hb[(size_t)n*HD + col] = b0;
    s += b0; q += b0*b0;
  }
  s += __shfl_xor(s,16); s += __shfl_xor(s,32);
  q += __shfl_xor(q,16); q += __shfl_xor(q,32);
  if (g==0){
    atomicAdd(&sum[col], s);
    atomicAdd(&sumsq[col], q);
  }
}

__global__ void k_normfin(const float* __restrict__ sum, const float* __restrict__ sumsq,
                          float* __restrict__ mu, float* __restrict__ rstd){
  int t=threadIdx.x;
  float m = sum[t]*(1.0f/NN);
  float var = sumsq[t]*(1.0f/NN) - m*m;
  mu[t]=m;
  rstd[t]=rsqrtf(fmaxf(var,0.0f)+EPSV);
}

// ---------------- decoder + outputs ----------------

__global__ void k_out(const float* __restrict__ hb, const float* __restrict__ mu, const float* __restrict__ rstd,
                      const float* __restrict__ pos, const float* __restrict__ v,
                      const float* __restrict__ W1, const float* __restrict__ b1,
                      const float* __restrict__ W2, const float* __restrict__ b2,
                      const float* __restrict__ domn, float* __restrict__ out){
  __shared__ alignas(16) float hs[4][HD*4];
  __shared__ alignas(16) float a1s[4][HD*4];
  int tid=threadIdx.x, wid=tid>>6, lane=tid&63;
  int gw=blockIdx.x*4+wid;
  int f0=lane, f1=lane+64;
  float* h4=hs[wid];
  float* a1p=a1s[wid];
  int n0=gw*4;
  float mu0=mu[f0], mu1=mu[f1], rs0=rstd[f0], rs1=rstd[f1];
  float4 hv0,hv1;
  hv0.x=(hb[(n0+0)*HD+f0]-mu0)*rs0; hv0.y=(hb[(n0+1)*HD+f0]-mu0)*rs0;
  hv0.z=(hb[(n0+2)*HD+f0]-mu0)*rs0; hv0.w=(hb[(n0+3)*HD+f0]-mu0)*rs0;
  hv1.x=(hb[(n0+0)*HD+f1]-mu1)*rs1; hv1.y=(hb[(n0+1)*HD+f1]-mu1)*rs1;
  hv1.z=(hb[(n0+2)*HD+f1]-mu1)*rs1; hv1.w=(hb[(n0+3)*HD+f1]-mu1)*rs1;
  *(float4*)&h4[f0*4]=hv0; *(float4*)&h4[f1*4]=hv1;
  float b1f0=b1[f0], b1f1=b1[f1];
  float zf0[4]={b1f0,b1f0,b1f0,b1f0}, zf1[4]={b1f1,b1f1,b1f1,b1f1};
  for (int k=0;k<HD;++k){
    float4 a = *(const float4*)&h4[k*4];
    float w0=W1[k*HD+f0], w1=W1[k*HD+f1];
    zf0[0]+=a.x*w0; zf1[0]+=a.x*w1;
    zf0[1]+=a.y*w0; zf1[1]+=a.y*w1;
    zf0[2]+=a.z*w0; zf1[2]+=a.z*w1;
    zf0[3]+=a.w*w0; zf1[3]+=a.w*w1;
  }
  *(float4*)&a1p[f0*4] = make_float4(relu_(zf0[0]),relu_(zf0[1]),relu_(zf0[2]),relu_(zf0[3]));
  *(float4*)&a1p[f1*4] = make_float4(relu_(zf1[0]),relu_(zf1[1]),relu_(zf1[2]),relu_(zf1[3]));
  if (lane < 36){
    int e = lane/9, j = lane - e*9;
    int n = n0+e;
    float p = b2[j];
    for (int k=0;k<HD;++k) p += a1p[k*4+e]*W2[k*9+j];
    if (j<3){
      p += pos[n*3+j];
      float d = domn[j];
      p = p - floorf(p/d)*d;
      out[n*3+j] = p;
    } else {
      p += v[n*6 + (j-3)];
      out[3*NN + n*6 + (j-3)] = p;
    }
  }
}

__global__ void k_macro(const float* __restrict__ sum, const float* __restrict__ mu, const float* __restrict__ rstd,
                        const float* __restrict__ W1, const float* __restrict__ b1,
                        const float* __restrict__ W2, const float* __restrict__ b2,
                        float* __restrict__ out){
  __shared__ float hm[HD];
  __shared__ float as[HD];
  int t=threadIdx.x;
  hm[t] = (sum[t]*(1.0f/NN) - mu[t])*rstd[t];
  __syncthreads();
  float z=b1[t];
  for (int k=0;k<HD;++k) z += hm[k]*W1[k*HD+t];
  as[t]=relu_(z);
  __syncthreads();
  if (t<3){
    float p=b2[t];
    for (int k=0;k<HD;++k) p += as[k]*W2[k*3+t];
    out[9*NN+t]=p;
  }
}

// ---------------- host launch ----------------

extern "C" void kernel_launch(void* const* d_in, const int* in_sizes, int n_in,
                              void* d_out, int out_size, void* d_ws, size_t ws_size,
                              hipStream_t stream) {
  const float* v    = (const float*)d_in[0];
  const float* pos  = (const float*)d_in[1];
  const float* r    = (const float*)d_in[2];
  const float* dom  = (const float*)d_in[3];
  const float* tt   = (const float*)d_in[4];
  const float* xg   = (const float*)d_in[5];
  const float* domn = (const float*)d_in[6];
  const float* tn   = (const float*)d_in[7];
  const int*   eidx = (const int*)d_in[8];
  const float* embW1 = (const float*)d_in[10];
  const float* embB1 = (const float*)d_in[11];
  const float* embW2 = (const float*)d_in[12];
  const float* embB2 = (const float*)d_in[13];
  const float* msgW1 = (const float*)d_in[14];
  const float* msgB1 = (const float*)d_in[15];
  const float* msgW2 = (const float*)d_in[16];
  const float* msgB2 = (const float*)d_in[17];
  const float* updW1 = (const float*)d_in[18];
  const float* updB1 = (const float*)d_in[19];
  const float* updW2 = (const float*)d_in[20];
  const float* updB2 = (const float*)d_in[21];
  const float* outW1 = (const float*)d_in[22];
  const float* outB1 = (const float*)d_in[23];
  const float* outW2 = (const float*)d_in[24];
  const float* outB2 = (const float*)d_in[25];
  const float* macW1 = (const float*)d_in[26];
  const float* macB1 = (const float*)d_in[27];
  const float* macW2 = (const float*)d_in[28];
  const float* macB2 = (const float*)d_in[29];
  float* out = (float*)d_out;
  float* ws  = (float*)d_ws;

  float* hb    = ws;
  float* P     = ws + 1280000;
  float* Q     = ws + 2560000;
  float* agg   = ws + 3840000;
  float* invc  = ws + 5120000;
  float* b1eff = ws + 5130000;   // 13*128
  float* sum   = ws + 5131664;
  float* sumsq = ws + 5131792;
  float* mu    = ws + 5131920;
  float* rstd  = ws + 5132048;
  int* counts  = (int*)(ws + 5132304);
  int* offs    = counts + NN;       // NN+1
  int* cursor  = offs + NN + 1;
  int* csr     = cursor + NN;       // NE

  const int* srcA = eidx;
  const int* dstA = eidx + NE;

  hipMemsetAsync(counts, 0, NN*sizeof(int), stream);
  hipMemsetAsync(cursor, 0, NN*sizeof(int), stream);

  k_degree<<<(NE+255)/256, 256, 0, stream>>>(dstA, counts);
  k_scan<<<1, 1024, 0, stream>>>(counts, offs, invc);
  k_place<<<(NE+255)/256, 256, 0, stream>>>(srcA, dstA, offs, cursor, csr);
  k_biasfold<<<14, 128, 0, stream>>>(dom, tt, xg, domn, tn, embW1, embB1, msgW1, msgB1, updW1, updB1,
                                     b1eff, mu, rstd);
  k_embed<<<625, 256, 0, stream>>>(r, v, embW1, b1eff, embW2, embB2, hb);

  for (int l=0; l<NL; ++l){
    k_hW<<<625,512,0,stream>>>(hb, mu, rstd, v, r, msgW1 + (size_t)l*157*HD, b1eff + (1+l)*HD, P, Q);
    k_edge<<<2500,256,0,stream>>>(P, Q, pos, dom, offs, csr,
        msgW1 + ((size_t)l*157+142)*HD,
        msgW2 + (size_t)l*HD*HD, msgB2 + l*HD, invc, agg, sum, sumsq);
    k_upd<<<625,512,0,stream>>>(hb, mu, rstd, agg,
        updW1 + (size_t)l*268*HD, b1eff + (7+l)*HD,
        updW2 + (size_t)l*HD*HD, updB2 + l*HD, sum, sumsq);
    k_normfin<<<1,128,0,stream>>>(sum, sumsq, mu, rstd);
  }

  k_out<<<625,256,0,stream>>>(hb, mu, rstd, pos, v, outW1, outB1, outW2, outB2, domn, out);
  k_macro<<<1,128,0,stream>>>(sum, mu, rstd, macW1, macB1, macW2, macB2, out);
}

// Round 14
// 840.685 us; speedup vs baseline: 1.6495x; 1.0178x over previous
//
#include <hip/hip_runtime.h>
#include <hip/hip_bf16.h>

#define NN 10000
#define NE 320000
#define HD 128
#define NL 6
#define EPSV 1e-5f

typedef _Float16 half8  __attribute__((ext_vector_type(8)));
typedef _Float16 half4v __attribute__((ext_vector_type(4)));
typedef float    f32x4  __attribute__((ext_vector_type(4)));

__device__ __forceinline__ float relu_(float x){ return fmaxf(x, 0.0f); }

// ---------------- degree / scan / place (CSR build) ----------------

__global__ void k_degree(const int* __restrict__ dst, int* __restrict__ counts){
  int e = blockIdx.x*256 + threadIdx.x;
  if (e < NE) atomicAdd(&counts[dst[e]], 1);
}

__global__ void k_scan(const int* __restrict__ counts, int* __restrict__ offs, float* __restrict__ invc){
  __shared__ int lds[1024];
  __shared__ int base_s;
  int tid = threadIdx.x;
  if (tid==0) base_s = 0;
  __syncthreads();
  for (int start=0; start<NN; start+=1024){
    int i = start+tid;
    int vv = (i<NN)? counts[i] : 0;
    lds[tid]=vv; __syncthreads();
    for (int off=1; off<1024; off<<=1){
      int t = (tid>=off)? lds[tid-off] : 0;
      __syncthreads();
      lds[tid] += t;
      __syncthreads();
    }
    int incl = lds[tid];
    if (i<NN){
      offs[i] = base_s + incl - vv;
      invc[i] = 1.0f / fmaxf((float)vv, 1.0f);
    }
    __syncthreads();
    if (tid==1023) base_s += lds[1023];
    __syncthreads();
  }
  if (tid==0) offs[NN] = base_s;
}

__global__ void k_place(const int* __restrict__ src, const int* __restrict__ dst,
                        const int* __restrict__ offs, int* __restrict__ cursor, int* __restrict__ csr){
  int e = blockIdx.x*256 + threadIdx.x;
  if (e < NE){
    int d = dst[e];
    int p = atomicAdd(&cursor[d], 1);
    csr[offs[d]+p] = src[e];
  }
}

// ---------------- fold gf into first-layer biases + init mu/rstd ----------------

__global__ void k_biasfold(const float* __restrict__ dom, const float* __restrict__ tt,
                           const float* __restrict__ xg, const float* __restrict__ domn,
                           const float* __restrict__ tn,
                           const float* __restrict__ embW1, const float* __restrict__ embB1,
                           const float* __restrict__ msgW1, const float* __restrict__ msgB1,
                           const float* __restrict__ updW1, const float* __restrict__ updB1,
                           float* __restrict__ b1eff, float* __restrict__ mu, float* __restrict__ rstd){
  float gf[12];
  gf[0]=dom[0]; gf[1]=dom[1]; gf[2]=dom[2]; gf[3]=tt[0];
  gf[4]=xg[0]; gf[5]=xg[1]; gf[6]=xg[2]; gf[7]=xg[3];
  gf[8]=domn[0]; gf[9]=domn[1]; gf[10]=domn[2]; gf[11]=tn[0];
  int b = blockIdx.x, t = threadIdx.x;
  if (b==0){
    float s = embB1[t];
    #pragma unroll
    for (int k=0;k<12;++k) s += gf[k]*embW1[(7+k)*HD + t];
    b1eff[t] = s;
  } else if (b<=6){
    int l=b-1;
    float s = msgB1[l*HD+t];
    #pragma unroll
    for (int k=0;k<12;++k) s += gf[k]*msgW1[((size_t)l*157 + 145+k)*HD + t];
    b1eff[(1+l)*HD + t] = s;
  } else if (b<=12){
    int l=b-7;
    float s = updB1[l*HD+t];
    #pragma unroll
    for (int k=0;k<12;++k) s += gf[k]*updW1[((size_t)l*268 + 256+k)*HD + t];
    b1eff[(7+l)*HD + t] = s;
  } else {
    mu[t] = 0.f;
    rstd[t] = 1.f;
  }
}

// ---------------- embedding via fp16-split MFMA (k_upd template) ----------------
// 625 blocks x 512 threads; block = 16 nodes; wave w owns cols [16w,16w+16).
// a1 = relu([r,v]@W1[0:7] + b1eff) computed scalar fp32 (K=7), hi/lo -> LDS;
// GEMM2 (K=128, 3-term fp16 split, embW2 B-frags in registers); hb = relu(.+b2).

__global__ __launch_bounds__(512,1) void k_embed(
    const float* __restrict__ r, const float* __restrict__ v,
    const float* __restrict__ W1, const float* __restrict__ b1e,
    const float* __restrict__ W2, const float* __restrict__ b2,
    float* __restrict__ hb){
  __shared__ alignas(16) _Float16 Ahi[16*136];
  __shared__ alignas(16) _Float16 Alo[16*136];
  int tid = threadIdx.x;
  int n0 = blockIdx.x*16;
  if (tid < 256){
    int node = tid>>4, chunk = tid&15;
    int n = n0 + node;
    int f = chunk*8;
    float in7[7];
    in7[0]=r[n];
    #pragma unroll
    for (int k=0;k<6;++k) in7[1+k]=v[n*6+k];
    half8 ah, al;
    #pragma unroll
    for (int j=0;j<8;++j){
      float z = b1e[f+j];
      #pragma unroll
      for (int k=0;k<7;++k) z += in7[k]*W1[k*HD + f+j];
      float a = fmaxf(z, 0.f);
      _Float16 h = (_Float16)a;
      ah[j] = h; al[j] = (_Float16)(a - (float)h);
    }
    *(half8*)&Ahi[node*136 + f] = ah;
    *(half8*)&Alo[node*136 + f] = al;
  }
  int wid = tid>>6, lane = tid&63, g = lane>>4, c = lane&15;
  int col = 16*wid + c;
  // B-frags (verified k_upd pattern): B[k = ks*32 + g*8 + j][col]
  half8 bh[4], bl[4];
  #pragma unroll
  for (int ks=0; ks<4; ++ks){
    half8 fh, fl;
    #pragma unroll
    for (int j=0;j<8;++j){
      float w = W2[(size_t)(ks*32 + g*8 + j)*HD + col];
      _Float16 h = (_Float16)w;
      fh[j]=h; fl[j]=(_Float16)(w - (float)h);
    }
    bh[ks]=fh; bl[ks]=fl;
  }
  float b2c = b2[col];
  f32x4 zero4 = {0.f,0.f,0.f,0.f};
  __syncthreads();
  f32x4 d = zero4;
  #pragma unroll
  for (int ks=0; ks<4; ++ks){
    half8 ah = *(const half8*)&Ahi[c*136 + ks*32 + g*8];
    half8 al = *(const half8*)&Alo[c*136 + ks*32 + g*8];
    d = __builtin_amdgcn_mfma_f32_16x16x32_f16(ah, bh[ks], d, 0,0,0);
    d = __builtin_amdgcn_mfma_f32_16x16x32_f16(al, bh[ks], d, 0,0,0);
    d = __builtin_amdgcn_mfma_f32_16x16x32_f16(ah, bl[ks], d, 0,0,0);
  }
  #pragma unroll
  for (int jj=0;jj<4;++jj){
    int n = n0 + g*4 + jj;
    hb[(size_t)n*HD + col] = fmaxf(d[jj] + b2c, 0.f);
  }
}

// ---------------- P/Q via fp16-split MFMA (k_upd template) ----------------
// 625 blocks x 512 threads; block = 16 nodes; wave w owns cols [16w,16w+16).

__global__ __launch_bounds__(512,1) void k_hW(
    const float* __restrict__ hb, const float* __restrict__ mu, const float* __restrict__ rstd,
    const float* __restrict__ v, const float* __restrict__ r,
    const float* __restrict__ W, const float* __restrict__ b1e,
    float* __restrict__ P, float* __restrict__ Q){
  __shared__ alignas(16) _Float16 Xhi[16*136];
  __shared__ alignas(16) _Float16 Xlo[16*136];
  int tid = threadIdx.x;
  int n0 = blockIdx.x*16;
  if (tid < 256){
    int node = tid>>4, chunk = tid&15;
    int n = n0 + node;
    int f = chunk*8;
    half8 xh, xl;
    #pragma unroll
    for (int j=0;j<8;++j){
      float x = (hb[(size_t)n*HD + f+j] - mu[f+j]) * rstd[f+j];
      _Float16 h = (_Float16)x;
      xh[j] = h; xl[j] = (_Float16)(x - (float)h);
    }
    *(half8*)&Xhi[node*136 + f] = xh;
    *(half8*)&Xlo[node*136 + f] = xl;
  }
  int wid = tid>>6, lane = tid&63, g = lane>>4, c = lane&15;
  int col = 16*wid + c;
  half8 bh[4], bl[4];
  #pragma unroll
  for (int ks=0; ks<4; ++ks){
    half8 fh, fl;
    #pragma unroll
    for (int j=0;j<8;++j){
      float w = W[(size_t)(ks*32 + g*8 + j)*HD + col];
      _Float16 h = (_Float16)w;
      fh[j]=h; fl[j]=(_Float16)(w - (float)h);
    }
    bh[ks]=fh; bl[ks]=fl;
  }
  float wvi[6], wvj[6];
  #pragma unroll
  for (int x=0;x<6;++x){
    wvi[x]=W[(size_t)(128+x)*HD+col];
    wvj[x]=W[(size_t)(134+x)*HD+col];
  }
  float wri=W[(size_t)140*HD+col], wrj=W[(size_t)141*HD+col];
  float b1c=b1e[col];
  f32x4 zero4 = {0.f,0.f,0.f,0.f};
  __syncthreads();
  f32x4 d = zero4;
  #pragma unroll
  for (int ks=0; ks<4; ++ks){
    half8 ah = *(const half8*)&Xhi[c*136 + ks*32 + g*8];
    half8 al = *(const half8*)&Xlo[c*136 + ks*32 + g*8];
    d = __builtin_amdgcn_mfma_f32_16x16x32_f16(ah, bh[ks], d, 0,0,0);
    d = __builtin_amdgcn_mfma_f32_16x16x32_f16(al, bh[ks], d, 0,0,0);
    d = __builtin_amdgcn_mfma_f32_16x16x32_f16(ah, bl[ks], d, 0,0,0);
  }
  #pragma unroll
  for (int jj=0;jj<4;++jj){
    int n = n0 + g*4 + jj;
    float m = d[jj];
    float p = m + b1c, q = -m;
    #pragma unroll
    for (int x=0;x<6;++x){
      float vx = v[n*6+x];
      p += vx*wvi[x]; q += vx*wvj[x];
    }
    float rn = r[n];
    p += rn*wri; q += rn*wrj;
    P[(size_t)n*HD+col]=p;
    Q[(size_t)n*HD+col]=q;
  }
}

// ---------------- edge MLP via fp16-split MFMA, wave-cooperative ----------------
// 5000 blocks x 2 dst nodes. Single a1 buffer, TWO barriers per tile (proven protocol).

__global__ __launch_bounds__(256,2) void k_edge(
    const float* __restrict__ P, const float* __restrict__ Q,
    const float* __restrict__ pos, const float* __restrict__ dom,
    const int* __restrict__ offs, const int* __restrict__ csr,
    const float* __restrict__ Wpd, const float* __restrict__ W2, const float* __restrict__ b2,
    const float* __restrict__ invc, float* __restrict__ agg,
    float* __restrict__ zsum, float* __restrict__ zsumsq){
  __shared__ alignas(16) _Float16 w1pd[128*40];     // [f][k]: k0..2 Whi, k3..5 Whi, k6..8 Wlo, rest 0; stride 40
  __shared__ alignas(16) _Float16 a1hi[16*136];     // block-shared [edge][f]
  __shared__ alignas(16) _Float16 a1lo[16*136];
  int tid = threadIdx.x;
  if (blockIdx.x==0 && tid<HD){ zsum[tid]=0.f; zsumsq[tid]=0.f; }
  if (tid < 128){
    int f = tid;
    #pragma unroll
    for (int k=0;k<32;++k) w1pd[f*40+k] = (_Float16)0.f;
    #pragma unroll
    for (int x=0;x<3;++x){
      float w = Wpd[x*HD + f];
      _Float16 h = (_Float16)w;
      w1pd[f*40 + x]     = h;
      w1pd[f*40 + 3 + x] = h;
      w1pd[f*40 + 6 + x] = (_Float16)(w - (float)h);
    }
  }
  int wid = tid>>6, lane = tid&63, g = lane>>4, c = lane&15;
  int t0 = 2*wid, t1 = 2*wid+1;
  half8 w2h[4][2], w2l[4][2];
  #pragma unroll
  for (int ks=0; ks<4; ++ks){
    #pragma unroll
    for (int tt=0; tt<2; ++tt){
      int col = 16*(2*wid+tt) + c;
      half8 fh, fl;
      #pragma unroll
      for (int j=0;j<8;++j){
        float w = W2[(ks*32 + g*8 + j)*HD + col];
        _Float16 h = (_Float16)w;
        fh[j] = h;
        fl[j] = (_Float16)(w - (float)h);
      }
      w2h[ks][tt] = fh;
      w2l[ks][tt] = fl;
    }
  }
  float b2v0 = b2[16*t0 + c], b2v1 = b2[16*t1 + c];
  float dm0=dom[0], dm1=dom[1], dm2=dom[2];
  f32x4 zero4 = {0.f,0.f,0.f,0.f};
  __syncthreads();
  int n0 = blockIdx.x*2;
  for (int n = n0; n < n0+2; ++n){
    f32x4 pv0 = *(const f32x4*)(P + (size_t)n*HD + 16*t0 + 4*g);
    f32x4 pv1 = *(const f32x4*)(P + (size_t)n*HD + 16*t1 + 4*g);
    float pn0=pos[n*3+0], pn1=pos[n*3+1], pn2=pos[n*3+2];
    float acc0=0.f, acc1=0.f;
    int ib=offs[n], ie=offs[n+1];
    for (int base=ib; base<ie; base+=16){
      int nb = ie - base; if (nb>16) nb = 16;
      int sA = csr[base + ((c<nb)? c : nb-1)];
      float q0=pos[sA*3+0], q1=pos[sA*3+1], q2=pos[sA*3+2];
      float pd0,pd1,pd2;
      { float diff,sh,ds;
        diff=pn0-q0; sh=(pn0<q0)?-dm0:dm0; ds=diff-sh; pd0=(fabsf(diff)<fabsf(ds))?diff:ds;
        diff=pn1-q1; sh=(pn1<q1)?-dm1:dm1; ds=diff-sh; pd1=(fabsf(diff)<fabsf(ds))?diff:ds;
        diff=pn2-q2; sh=(pn2<q2)?-dm2:dm2; ds=diff-sh; pd2=(fabsf(diff)<fabsf(ds))?diff:ds;
      }
      _Float16 p0h = (_Float16)pd0, p1h = (_Float16)pd1, p2h = (_Float16)pd2;
      _Float16 p0l = (_Float16)(pd0 - (float)p0h);
      _Float16 p1l = (_Float16)(pd1 - (float)p1h);
      _Float16 p2l = (_Float16)(pd2 - (float)p2h);
      half8 pdf;
      #pragma unroll
      for (int j=0;j<8;++j) pdf[j]=(_Float16)0.f;
      if (g==0){ pdf[0]=p0h; pdf[1]=p1h; pdf[2]=p2h; pdf[3]=p0l; pdf[4]=p1l; pdf[5]=p2l; pdf[6]=p0h; pdf[7]=p1h; }
      else if (g==1){ pdf[0]=p2h; }
      half8 w1f0 = *(const half8*)&w1pd[(16*t0 + c)*40 + g*8];
      half8 w1f1 = *(const half8*)&w1pd[(16*t1 + c)*40 + g*8];
      f32x4 d0 = __builtin_amdgcn_mfma_f32_16x16x32_f16(w1f0, pdf, zero4, 0,0,0);
      f32x4 d1 = __builtin_amdgcn_mfma_f32_16x16x32_f16(w1f1, pdf, zero4, 0,0,0);
      const float* Qs = Q + (size_t)sA*HD;
      f32x4 qv0 = *(const f32x4*)(Qs + 16*t0 + 4*g);
      f32x4 qv1 = *(const f32x4*)(Qs + 16*t1 + 4*g);
      half4v h0, l0, h1, l1;
      #pragma unroll
      for (int j=0;j<4;++j){
        float a = fmaxf(d0[j] + pv0[j] + qv0[j], 0.f);
        _Float16 hh = (_Float16)a;
        h0[j] = hh; l0[j] = (_Float16)(a - (float)hh);
        float b = fmaxf(d1[j] + pv1[j] + qv1[j], 0.f);
        _Float16 hb2 = (_Float16)b;
        h1[j] = hb2; l1[j] = (_Float16)(b - (float)hb2);
      }
      *(half4v*)&a1hi[c*136 + 16*t0 + 4*g] = h0;
      *(half4v*)&a1lo[c*136 + 16*t0 + 4*g] = l0;
      *(half4v*)&a1hi[c*136 + 16*t1 + 4*g] = h1;
      *(half4v*)&a1lo[c*136 + 16*t1 + 4*g] = l1;
      __syncthreads();
      f32x4 m0 = zero4, m1 = zero4;
      #pragma unroll
      for (int ks=0; ks<4; ++ks){
        half8 ah = *(const half8*)&a1hi[c*136 + ks*32 + g*8];
        half8 al = *(const half8*)&a1lo[c*136 + ks*32 + g*8];
        m0 = __builtin_amdgcn_mfma_f32_16x16x32_f16(ah, w2h[ks][0], m0, 0,0,0);
        m0 = __builtin_amdgcn_mfma_f32_16x16x32_f16(al, w2h[ks][0], m0, 0,0,0);
        m0 = __builtin_amdgcn_mfma_f32_16x16x32_f16(ah, w2l[ks][0], m0, 0,0,0);
        m1 = __builtin_amdgcn_mfma_f32_16x16x32_f16(ah, w2h[ks][1], m1, 0,0,0);
        m1 = __builtin_amdgcn_mfma_f32_16x16x32_f16(al, w2h[ks][1], m1, 0,0,0);
        m1 = __builtin_amdgcn_mfma_f32_16x16x32_f16(ah, w2l[ks][1], m1, 0,0,0);
      }
      if (nb == 16){
        acc0 += fmaxf(m0[0]+b2v0,0.f)+fmaxf(m0[1]+b2v0,0.f)+fmaxf(m0[2]+b2v0,0.f)+fmaxf(m0[3]+b2v0,0.f);
        acc1 += fmaxf(m1[0]+b2v1,0.f)+fmaxf(m1[1]+b2v1,0.f)+fmaxf(m1[2]+b2v1,0.f)+fmaxf(m1[3]+b2v1,0.f);
      } else {
        #pragma unroll
        for (int j=0;j<4;++j){
          if (4*g+j < nb){
            acc0 += fmaxf(m0[j]+b2v0, 0.f);
            acc1 += fmaxf(m1[j]+b2v1, 0.f);
          }
        }
      }
      __syncthreads();
    }
    acc0 += __shfl_xor(acc0, 16); acc0 += __shfl_xor(acc0, 32);
    acc1 += __shfl_xor(acc1, 16); acc1 += __shfl_xor(acc1, 32);
    if (g==0){
      float ic = invc[n];
      agg[n*HD + 16*t0 + c] = acc0*ic;
      agg[n*HD + 16*t1 + c] = acc1*ic;
    }
  }
}

// ---------------- update MLP via fp16-split MFMA ----------------
// 625 blocks x 512 threads; block = 16 nodes; wave w owns cols [16w,16w+16).

__global__ __launch_bounds__(512,1) void k_upd(
    float* __restrict__ hb, const float* __restrict__ mu, const float* __restrict__ rstd,
    const float* __restrict__ agg,
    const float* __restrict__ U1, const float* __restrict__ b1e,
    const float* __restrict__ U2, const float* __restrict__ bs2,
    float* __restrict__ sum, float* __restrict__ sumsq){
  __shared__ alignas(16) _Float16 Xhi[16*264];
  __shared__ alignas(16) _Float16 Xlo[16*264];
  __shared__ alignas(16) _Float16 Ahi[16*136];
  __shared__ alignas(16) _Float16 Alo[16*136];
  int tid = threadIdx.x;
  int n0 = blockIdx.x*16;
  {
    int node = tid>>5, chunk = tid&31;
    int n = n0 + node;
    int f = chunk*8;
    half8 xh, xl;
    if (f < 128){
      #pragma unroll
      for (int j=0;j<8;++j){
        float x = (hb[(size_t)n*HD + f+j] - mu[f+j]) * rstd[f+j];
        _Float16 h = (_Float16)x;
        xh[j] = h; xl[j] = (_Float16)(x - (float)h);
      }
    } else {
      #pragma unroll
      for (int j=0;j<8;++j){
        float x = agg[(size_t)n*HD + (f-128)+j];
        _Float16 h = (_Float16)x;
        xh[j] = h; xl[j] = (_Float16)(x - (float)h);
      }
    }
    *(half8*)&Xhi[node*264 + f] = xh;
    *(half8*)&Xlo[node*264 + f] = xl;
  }
  int wid = tid>>6, lane = tid&63, g = lane>>4, c = lane&15;
  int col = 16*wid + c;
  half8 b1h[8], b1l[8], b2h[4], b2l[4];
  #pragma unroll
  for (int ks=0; ks<8; ++ks){
    half8 fh, fl;
    #pragma unroll
    for (int j=0;j<8;++j){
      float w = U1[(size_t)(ks*32 + g*8 + j)*HD + col];
      _Float16 h = (_Float16)w;
      fh[j]=h; fl[j]=(_Float16)(w - (float)h);
    }
    b1h[ks]=fh; b1l[ks]=fl;
  }
  #pragma unroll
  for (int ks=0; ks<4; ++ks){
    half8 fh, fl;
    #pragma unroll
    for (int j=0;j<8;++j){
      float w = U2[(size_t)(ks*32 + g*8 + j)*HD + col];
      _Float16 h = (_Float16)w;
      fh[j]=h; fl[j]=(_Float16)(w - (float)h);
    }
    b2h[ks]=fh; b2l[ks]=fl;
  }
  f32x4 zero4 = {0.f,0.f,0.f,0.f};
  __syncthreads();
  f32x4 d = zero4;
  #pragma unroll
  for (int ks=0; ks<8; ++ks){
    half8 ah = *(const half8*)&Xhi[c*264 + ks*32 + g*8];
    half8 al = *(const half8*)&Xlo[c*264 + ks*32 + g*8];
    d = __builtin_amdgcn_mfma_f32_16x16x32_f16(ah, b1h[ks], d, 0,0,0);
    d = __builtin_amdgcn_mfma_f32_16x16x32_f16(al, b1h[ks], d, 0,0,0);
    d = __builtin_amdgcn_mfma_f32_16x16x32_f16(ah, b1l[ks], d, 0,0,0);
  }
  {
    float bb = b1e[col];
    #pragma unroll
    for (int jj=0;jj<4;++jj){
      float a = fmaxf(d[jj] + bb, 0.f);
      _Float16 h = (_Float16)a;
      Ahi[(g*4+jj)*136 + col] = h;
      Alo[(g*4+jj)*136 + col] = (_Float16)(a - (float)h);
    }
  }
  __syncthreads();
  f32x4 u = zero4;
  #pragma unroll
  for (int ks=0; ks<4; ++ks){
    half8 ah = *(const half8*)&Ahi[c*136 + ks*32 + g*8];
    half8 al = *(const half8*)&Alo[c*136 + ks*32 + g*8];
    u = __builtin_amdgcn_mfma_f32_16x16x32_f16(ah, b2h[ks], u, 0,0,0);
    u = __builtin_amdgcn_mfma_f32_16x16x32_f16(al, b2h[ks], u, 0,0,0);
    u = __builtin_amdgcn_mfma_f32_16x16x32_f16(ah, b2l[ks], u, 0,0,0);
  }
  float bc = bs2[col];
  float mc = mu[col], rc = rstd[col];
  float s=0.f, q=0.f;
  #pragma unroll
  for (int jj=0;jj<4;++jj){
    int n = n0 + g*4 + jj;
    float hn = (hb[(size_t)n*HD + col] - mc)*rc;
    float b0 = hn + fmaxf(u[jj] + bc, 0.f);
    hb[(size_t)n*HD + col] = b0;
    s += b0; q += b0*b0;
  }
  s += __shfl_xor(s,16); s += __shfl_xor(s,32);
  q += __shfl_xor(q,16); q += __shfl_xor(q,32);
  if (g==0){
    atomicAdd(&sum[col], s);
    atomicAdd(&sumsq[col], q);
  }
}

__global__ void k_normfin(const float* __restrict__ sum, const float* __restrict__ sumsq,
                          float* __restrict__ mu, float* __restrict__ rstd){
  int t=threadIdx.x;
  float m = sum[t]*(1.0f/NN);
  float var = sumsq[t]*(1.0f/NN) - m*m;
  mu[t]=m;
  rstd[t]=rsqrtf(fmaxf(var,0.0f)+EPSV);
}

// ---------------- decoder + outputs ----------------

__global__ void k_out(const float* __restrict__ hb, const float* __restrict__ mu, const float* __restrict__ rstd,
                      const float* __restrict__ pos, const float* __restrict__ v,
                      const float* __restrict__ W1, const float* __restrict__ b1,
                      const float* __restrict__ W2, const float* __restrict__ b2,
                      const float* __restrict__ domn, float* __restrict__ out){
  __shared__ alignas(16) float hs[4][HD*4];
  __shared__ alignas(16) float a1s[4][HD*4];
  int tid=threadIdx.x, wid=tid>>6, lane=tid&63;
  int gw=blockIdx.x*4+wid;
  int f0=lane, f1=lane+64;
  float* h4=hs[wid];
  float* a1p=a1s[wid];
  int n0=gw*4;
  float mu0=mu[f0], mu1=mu[f1], rs0=rstd[f0], rs1=rstd[f1];
  float4 hv0,hv1;
  hv0.x=(hb[(n0+0)*HD+f0]-mu0)*rs0; hv0.y=(hb[(n0+1)*HD+f0]-mu0)*rs0;
  hv0.z=(hb[(n0+2)*HD+f0]-mu0)*rs0; hv0.w=(hb[(n0+3)*HD+f0]-mu0)*rs0;
  hv1.x=(hb[(n0+0)*HD+f1]-mu1)*rs1; hv1.y=(hb[(n0+1)*HD+f1]-mu1)*rs1;
  hv1.z=(hb[(n0+2)*HD+f1]-mu1)*rs1; hv1.w=(hb[(n0+3)*HD+f1]-mu1)*rs1;
  *(float4*)&h4[f0*4]=hv0; *(float4*)&h4[f1*4]=hv1;
  float b1f0=b1[f0], b1f1=b1[f1];
  float zf0[4]={b1f0,b1f0,b1f0,b1f0}, zf1[4]={b1f1,b1f1,b1f1,b1f1};
  for (int k=0;k<HD;++k){
    float4 a = *(const float4*)&h4[k*4];
    float w0=W1[k*HD+f0], w1=W1[k*HD+f1];
    zf0[0]+=a.x*w0; zf1[0]+=a.x*w1;
    zf0[1]+=a.y*w0; zf1[1]+=a.y*w1;
    zf0[2]+=a.z*w0; zf1[2]+=a.z*w1;
    zf0[3]+=a.w*w0; zf1[3]+=a.w*w1;
  }
  *(float4*)&a1p[f0*4] = make_float4(relu_(zf0[0]),relu_(zf0[1]),relu_(zf0[2]),relu_(zf0[3]));
  *(float4*)&a1p[f1*4] = make_float4(relu_(zf1[0]),relu_(zf1[1]),relu_(zf1[2]),relu_(zf1[3]));
  if (lane < 36){
    int e = lane/9, j = lane - e*9;
    int n = n0+e;
    float p = b2[j];
    for (int k=0;k<HD;++k) p += a1p[k*4+e]*W2[k*9+j];
    if (j<3){
      p += pos[n*3+j];
      float d = domn[j];
      p = p - floorf(p/d)*d;
      out[n*3+j] = p;
    } else {
      p += v[n*6 + (j-3)];
      out[3*NN + n*6 + (j-3)] = p;
    }
  }
}

__global__ void k_macro(const float* __restrict__ sum, const float* __restrict__ mu, const float* __restrict__ rstd,
                        const float* __restrict__ W1, const float* __restrict__ b1,
                        const float* __restrict__ W2, const float* __restrict__ b2,
                        float* __restrict__ out){
  __shared__ float hm[HD];
  __shared__ float as[HD];
  int t=threadIdx.x;
  hm[t] = (sum[t]*(1.0f/NN) - mu[t])*rstd[t];
  __syncthreads();
  float z=b1[t];
  for (int k=0;k<HD;++k) z += hm[k]*W1[k*HD+t];
  as[t]=relu_(z);
  __syncthreads();
  if (t<3){
    float p=b2[t];
    for (int k=0;k<HD;++k) p += as[k]*W2[k*3+t];
    out[9*NN+t]=p;
  }
}

// ---------------- host launch ----------------

extern "C" void kernel_launch(void* const* d_in, const int* in_sizes, int n_in,
                              void* d_out, int out_size, void* d_ws, size_t ws_size,
                              hipStream_t stream) {
  const float* v    = (const float*)d_in[0];
  const float* pos  = (const float*)d_in[1];
  const float* r    = (const float*)d_in[2];
  const float* dom  = (const float*)d_in[3];
  const float* tt   = (const float*)d_in[4];
  const float* xg   = (const float*)d_in[5];
  const float* domn = (const float*)d_in[6];
  const float* tn   = (const float*)d_in[7];
  const int*   eidx = (const int*)d_in[8];
  const float* embW1 = (const float*)d_in[10];
  const float* embB1 = (const float*)d_in[11];
  const float* embW2 = (const float*)d_in[12];
  const float* embB2 = (const float*)d_in[13];
  const float* msgW1 = (const float*)d_in[14];
  const float* msgB1 = (const float*)d_in[15];
  const float* msgW2 = (const float*)d_in[16];
  const float* msgB2 = (const float*)d_in[17];
  const float* updW1 = (const float*)d_in[18];
  const float* updB1 = (const float*)d_in[19];
  const float* updW2 = (const float*)d_in[20];
  const float* updB2 = (const float*)d_in[21];
  const float* outW1 = (const float*)d_in[22];
  const float* outB1 = (const float*)d_in[23];
  const float* outW2 = (const float*)d_in[24];
  const float* outB2 = (const float*)d_in[25];
  const float* macW1 = (const float*)d_in[26];
  const float* macB1 = (const float*)d_in[27];
  const float* macW2 = (const float*)d_in[28];
  const float* macB2 = (const float*)d_in[29];
  float* out = (float*)d_out;
  float* ws  = (float*)d_ws;

  float* hb    = ws;
  float* P     = ws + 1280000;
  float* Q     = ws + 2560000;
  float* agg   = ws + 3840000;
  float* invc  = ws + 5120000;
  float* b1eff = ws + 5130000;   // 13*128
  float* sum   = ws + 5131664;
  float* sumsq = ws + 5131792;
  float* mu    = ws + 5131920;
  float* rstd  = ws + 5132048;
  int* counts  = (int*)(ws + 5132304);
  int* offs    = counts + NN;       // NN+1
  int* cursor  = offs + NN + 1;
  int* csr     = cursor + NN;       // NE

  const int* srcA = eidx;
  const int* dstA = eidx + NE;

  hipMemsetAsync(counts, 0, NN*sizeof(int), stream);
  hipMemsetAsync(cursor, 0, NN*sizeof(int), stream);

  k_degree<<<(NE+255)/256, 256, 0, stream>>>(dstA, counts);
  k_scan<<<1, 1024, 0, stream>>>(counts, offs, invc);
  k_place<<<(NE+255)/256, 256, 0, stream>>>(srcA, dstA, offs, cursor, csr);
  k_biasfold<<<14, 128, 0, stream>>>(dom, tt, xg, domn, tn, embW1, embB1, msgW1, msgB1, updW1, updB1,
                                     b1eff, mu, rstd);
  k_embed<<<625, 512, 0, stream>>>(r, v, embW1, b1eff, embW2, embB2, hb);

  for (int l=0; l<NL; ++l){
    k_hW<<<625,512,0,stream>>>(hb, mu, rstd, v, r, msgW1 + (size_t)l*157*HD, b1eff + (1+l)*HD, P, Q);
    k_edge<<<5000,256,0,stream>>>(P, Q, pos, dom, offs, csr,
        msgW1 + ((size_t)l*157+142)*HD,
        msgW2 + (size_t)l*HD*HD, msgB2 + l*HD, invc, agg, sum, sumsq);
    k_upd<<<625,512,0,stream>>>(hb, mu, rstd, agg,
        updW1 + (size_t)l*268*HD, b1eff + (7+l)*HD,
        updW2 + (size_t)l*HD*HD, updB2 + l*HD, sum, sumsq);
    k_normfin<<<1,128,0,stream>>>(sum, sumsq, mu, rstd);
  }

  k_out<<<625,256,0,stream>>>(hb, mu, rstd, pos, v, outW1, outB1, outW2, outB2, domn, out);
  k_macro<<<1,128,0,stream>>>(sum, mu, rstd, macW1, macB1, macW2, macB2, out);
}